// Round 1
// baseline (2373.239 us; speedup 1.0000x reference)
//
#include <hip/hip_runtime.h>
#include <hip/hip_bf16.h>
#include <stdint.h>

#define NB 4
#define CQ 512
#define CK 256
#define TT 4096
#define SCALE_QK 0.21022410381342863f  // 512^-0.25

using bf16x8 = __attribute__((ext_vector_type(8))) short;
using f32x4  = __attribute__((ext_vector_type(4))) float;
using u32x4  = __attribute__((ext_vector_type(4))) unsigned int;
typedef unsigned short u16;

__device__ __forceinline__ u16 f2bf(float f) {
    union { float f; unsigned u; } v; v.f = f;
    return (u16)((v.u + 0x7fffu + ((v.u >> 16) & 1u)) >> 16);
}
__device__ __forceinline__ float bf2f(u16 h) {
    union { float f; unsigned u; } v; v.u = ((unsigned)h) << 16;
    return v.f;
}
__device__ __forceinline__ bf16x8 pack8(f32x4 a, f32x4 b) {
    bf16x8 r;
    r[0] = (short)f2bf(a[0]); r[1] = (short)f2bf(a[1]);
    r[2] = (short)f2bf(a[2]); r[3] = (short)f2bf(a[3]);
    r[4] = (short)f2bf(b[0]); r[5] = (short)f2bf(b[1]);
    r[6] = (short)f2bf(b[2]); r[7] = (short)f2bf(b[3]);
    return r;
}

// ---- 2x2 avg pool of key_feat (b,256,128,128) -> kdsT (b,4096,256) bf16 ----
__global__ __launch_bounds__(256) void pool_tr_kernel(const float* __restrict__ kf,
                                                      u16* __restrict__ kdsT) {
    int h = blockIdx.x, b = blockIdx.y;
    __shared__ u16 tile[64][264];  // [w][c], padded
    for (int idx = threadIdx.x; idx < 64 * 256; idx += 256) {
        int w = idx & 63, c = idx >> 6;
        const float* base = kf + (((size_t)b * CK + c) * 128 + 2 * h) * 128 + 2 * w;
        float2 r0 = *(const float2*)base;
        float2 r1 = *(const float2*)(base + 128);
        tile[w][c] = f2bf(0.25f * (r0.x + r0.y + r1.x + r1.y));
    }
    __syncthreads();
    for (int idx = threadIdx.x; idx < 64 * 32; idx += 256) {
        int w = idx >> 5, cg = (idx & 31) << 3;
        *(u32x4*)(kdsT + ((size_t)b * TT + h * 64 + w) * CK + cg) = *(const u32x4*)&tile[w][cg];
    }
}

// ---- GroupNorm stats -> per-channel scale/shift (folded affine) ----
template <int ISBF>
__global__ __launch_bounds__(256) void gn_stats_kernel(const void* __restrict__ xv,
        const float* __restrict__ gw, const float* __restrict__ gb,
        float* __restrict__ sc, float* __restrict__ sh) {
    int g = blockIdx.x, b = blockIdx.y;
    size_t base = ((size_t)b * CQ + g * 16) * TT;
    float s = 0.f, q = 0.f;
    for (int i = threadIdx.x * 4; i < 16 * TT; i += 256 * 4) {
        float v0, v1, v2, v3;
        if constexpr (ISBF) {
            const u16* x = (const u16*)xv;
            uint2 u = *(const uint2*)(x + base + i);
            v0 = bf2f((u16)(u.x & 0xffff)); v1 = bf2f((u16)(u.x >> 16));
            v2 = bf2f((u16)(u.y & 0xffff)); v3 = bf2f((u16)(u.y >> 16));
        } else {
            const float* x = (const float*)xv;
            f32x4 v = *(const f32x4*)(x + base + i);
            v0 = v[0]; v1 = v[1]; v2 = v[2]; v3 = v[3];
        }
        s += v0 + v1 + v2 + v3;
        q += v0 * v0 + v1 * v1 + v2 * v2 + v3 * v3;
    }
#pragma unroll
    for (int d = 1; d < 64; d <<= 1) { s += __shfl_xor(s, d, 64); q += __shfl_xor(q, d, 64); }
    __shared__ float shs[4], shq[4];
    int wid = threadIdx.x >> 6;
    if ((threadIdx.x & 63) == 0) { shs[wid] = s; shq[wid] = q; }
    __syncthreads();
    if (threadIdx.x < 16) {
        float S = shs[0] + shs[1] + shs[2] + shs[3];
        float Q = shq[0] + shq[1] + shq[2] + shq[3];
        const float inv = 1.f / (16.f * TT);
        float mean = S * inv, var = Q * inv - mean * mean;
        float rstd = rsqrtf(var + 1e-5f);
        int c = g * 16 + threadIdx.x;
        float w = gw[c] * rstd;
        sc[b * CQ + c] = w;
        sh[b * CQ + c] = gb[c] - mean * w;
    }
}

// ---- affine + transpose: in (b,512,T) -> out (b,T,512) bf16 ----
template <int ISBF>
__global__ __launch_bounds__(256) void affine_tr_kernel(const void* __restrict__ xv,
        const float* __restrict__ sc, const float* __restrict__ sh, u16* __restrict__ out) {
    int t0 = blockIdx.x * 64, c0 = blockIdx.y * 64, b = blockIdx.z;
    __shared__ u16 tile[64][72];  // [t][c]
    for (int idx = threadIdx.x; idx < 64 * 64; idx += 256) {
        int tl = idx & 63, cl = idx >> 6;
        int c = c0 + cl;
        float v;
        if constexpr (ISBF) v = bf2f(((const u16*)xv)[((size_t)b * CQ + c) * TT + t0 + tl]);
        else                v = ((const float*)xv)[((size_t)b * CQ + c) * TT + t0 + tl];
        tile[tl][cl] = f2bf(v * sc[b * CQ + c] + sh[b * CQ + c]);
    }
    __syncthreads();
    for (int idx = threadIdx.x; idx < 64 * 8; idx += 256) {
        int tl = idx >> 3, cg = (idx & 7) << 3;
        *(u32x4*)(out + ((size_t)b * TT + t0 + tl) * CQ + c0 + cg) = *(const u32x4*)&tile[tl][cg];
    }
}

// ---- GEMM: out[b,o,t] = sum_c W[o,c] * XT[b,t,c]  (natural-orientation) ----
// EPI 0: store bf16 (k_raw). EPI 1: +bias, store bf16 (vv). EPI 2: +bias+GN(query) residual, f32.
template <int EPI, int CONCAT>
__global__ __launch_bounds__(256) void gemm_wx_kernel(
        const float* __restrict__ W, const u16* __restrict__ X1, const u16* __restrict__ X2,
        int Ktot, const float* __restrict__ bias,
        u16* __restrict__ outb, float* __restrict__ outf,
        const float* __restrict__ query, const float* __restrict__ qsc,
        const float* __restrict__ qsh) {
    int b = blockIdx.z;
    int o_blk = blockIdx.x * 64, t_blk = blockIdx.y * 128;
    int wid = threadIdx.x >> 6, lane = threadIdx.x & 63;
    int lr = lane & 15, lg = lane >> 4;
    int o_base = o_blk + (wid >> 1) * 32;
    int t_base = t_blk + (wid & 1) * 64;
    f32x4 acc[2][4];
#pragma unroll
    for (int i = 0; i < 2; i++)
#pragma unroll
        for (int j = 0; j < 4; j++) acc[i][j] = f32x4{0.f, 0.f, 0.f, 0.f};
    int nk = Ktot >> 5;
    for (int kc = 0; kc < nk; kc++) {
        int c0 = (kc << 5) + lg * 8;
        bf16x8 am[2];
#pragma unroll
        for (int mi = 0; mi < 2; mi++) {
            const float* wp = W + (size_t)(o_base + mi * 16 + lr) * Ktot + c0;
            am[mi] = pack8(*(const f32x4*)wp, *(const f32x4*)(wp + 4));
        }
        bf16x8 bn[4];
#pragma unroll
        for (int ni = 0; ni < 4; ni++) {
            int t = t_base + ni * 16 + lr;
            const u16* xp;
            if (CONCAT) {
                xp = (c0 < 512) ? (X1 + ((size_t)b * TT + t) * 512 + c0)
                                : (X2 + ((size_t)b * TT + t) * 512 + (c0 - 512));
            } else {
                xp = X1 + ((size_t)b * TT + t) * Ktot + c0;
            }
            bn[ni] = *(const bf16x8*)xp;
        }
#pragma unroll
        for (int mi = 0; mi < 2; mi++)
#pragma unroll
            for (int ni = 0; ni < 4; ni++)
                acc[mi][ni] = __builtin_amdgcn_mfma_f32_16x16x32_bf16(am[mi], bn[ni], acc[mi][ni], 0, 0, 0);
    }
#pragma unroll
    for (int mi = 0; mi < 2; mi++) {
#pragma unroll
        for (int reg = 0; reg < 4; reg++) {
            int o = o_base + mi * 16 + 4 * lg + reg;
            float bv = (EPI >= 1) ? bias[o] : 0.f;
#pragma unroll
            for (int ni = 0; ni < 4; ni++) {
                int t = t_base + ni * 16 + lr;
                size_t oidx = ((size_t)b * CQ + o) * TT + t;
                float v = acc[mi][ni][reg] + bv;
                if (EPI == 2) {
                    outf[oidx] = v + query[oidx] * qsc[b * CQ + o] + qsh[b * CQ + o];
                } else {
                    outb[oidx] = f2bf(v);
                }
            }
        }
    }
}

// ---- swapped GEMM for qq/kk: D[b,t,o] = sum_c XT[b,t,c]*W[o,c]; store transposed layouts ----
__global__ __launch_bounds__(256) void gemm_qk_tr_kernel(
        const u16* __restrict__ qnT, const u16* __restrict__ knT,
        const float* __restrict__ W, const float* __restrict__ bias,
        u16* __restrict__ qqT, u16* __restrict__ kkT) {
    int b = blockIdx.z;
    int t_blk = blockIdx.x * 128, o_blk = blockIdx.y * 64;
    int wid = threadIdx.x >> 6, lane = threadIdx.x & 63;
    int lr = lane & 15, lg = lane >> 4;
    int t_base = t_blk + (wid >> 1) * 64;
    int o_base = o_blk + (wid & 1) * 32;
    f32x4 acc[4][2];
#pragma unroll
    for (int i = 0; i < 4; i++)
#pragma unroll
        for (int j = 0; j < 2; j++) acc[i][j] = f32x4{0.f, 0.f, 0.f, 0.f};
    for (int kc = 0; kc < 32; kc++) {
        int c0 = (kc << 5) + lg * 8;
        const u16* xb = (c0 < 512) ? qnT : knT;
        int cc = (c0 < 512) ? c0 : c0 - 512;
        bf16x8 am[4];
#pragma unroll
        for (int mi = 0; mi < 4; mi++)
            am[mi] = *(const bf16x8*)(xb + ((size_t)b * TT + t_base + mi * 16 + lr) * 512 + cc);
        bf16x8 bn[2];
#pragma unroll
        for (int ni = 0; ni < 2; ni++) {
            const float* wp = W + (size_t)(o_base + ni * 16 + lr) * 1024 + c0;
            bn[ni] = pack8(*(const f32x4*)wp, *(const f32x4*)(wp + 4));
        }
#pragma unroll
        for (int mi = 0; mi < 4; mi++)
#pragma unroll
            for (int ni = 0; ni < 2; ni++)
                acc[mi][ni] = __builtin_amdgcn_mfma_f32_16x16x32_bf16(am[mi], bn[ni], acc[mi][ni], 0, 0, 0);
    }
#pragma unroll
    for (int mi = 0; mi < 4; mi++)
#pragma unroll
        for (int ni = 0; ni < 2; ni++)
#pragma unroll
            for (int reg = 0; reg < 4; reg++) {
                int t = t_base + mi * 16 + 4 * lg + reg;
                int o = o_base + ni * 16 + lr;
                float v = (acc[mi][ni][reg] + bias[o]) * SCALE_QK;
                if (o < 512) qqT[((size_t)b * TT + t) * 512 + o] = f2bf(v);
                else         kkT[((size_t)b * TT + t) * 512 + (o - 512)] = f2bf(v);
            }
}

// ---- flash attention: logits = WM .* (qq^T kk), softmax over s, aT = softmax @ vv^T ----
__global__ __launch_bounds__(256, 1) void flash_kernel(
        const u16* __restrict__ qqT, const u16* __restrict__ kkT, const u16* __restrict__ vv,
        const float* __restrict__ WM, u16* __restrict__ aT) {
    int b = blockIdx.y;
    int wid = threadIdx.x >> 6, lane = threadIdx.x & 63;
    int lr = lane & 15, lg = lane >> 4;
    int t0 = blockIdx.x * 64 + wid * 16;  // wave's 16 t-rows
    __shared__ u16 p_lds[4][16][72];      // wave-private P tile [t][s]
    bf16x8 qf[16];
    {
        const u16* qrow = qqT + ((size_t)b * TT + t0 + lr) * CQ + lg * 8;
#pragma unroll
        for (int kc = 0; kc < 16; kc++) qf[kc] = *(const bf16x8*)(qrow + kc * 32);
    }
    f32x4 acc[32];
#pragma unroll
    for (int i = 0; i < 32; i++) acc[i] = f32x4{0.f, 0.f, 0.f, 0.f};
    float m[4], l[4];
#pragma unroll
    for (int r = 0; r < 4; r++) { m[r] = -1e30f; l[r] = 0.f; }

    for (int s0 = 0; s0 < TT; s0 += 64) {
        // S = Q^T K for 16t x 64s
        f32x4 sacc[4];
#pragma unroll
        for (int fs = 0; fs < 4; fs++) sacc[fs] = f32x4{0.f, 0.f, 0.f, 0.f};
        const u16* krow = kkT + ((size_t)b * TT + s0 + lr) * CQ + lg * 8;
#pragma unroll
        for (int kc = 0; kc < 16; kc++) {
#pragma unroll
            for (int fs = 0; fs < 4; fs++) {
                bf16x8 kfr = *(const bf16x8*)(krow + (size_t)fs * 16 * CQ + kc * 32);
                sacc[fs] = __builtin_amdgcn_mfma_f32_16x16x32_bf16(qf[kc], kfr, sacc[fs], 0, 0, 0);
            }
        }
        // logits = WM * S ; row max
        float lgt[4][4];
        float rmax[4];
#pragma unroll
        for (int r = 0; r < 4; r++) rmax[r] = -1e30f;
        const float* wmrow = WM + ((size_t)b * TT + t0 + 4 * lg) * TT + s0 + lr;
#pragma unroll
        for (int fs = 0; fs < 4; fs++)
#pragma unroll
            for (int reg = 0; reg < 4; reg++) {
                float wv = wmrow[(size_t)reg * TT + fs * 16];
                float v = sacc[fs][reg] * wv;
                lgt[fs][reg] = v;
                rmax[reg] = fmaxf(rmax[reg], v);
            }
#pragma unroll
        for (int d = 1; d < 16; d <<= 1)
#pragma unroll
            for (int reg = 0; reg < 4; reg++)
                rmax[reg] = fmaxf(rmax[reg], __shfl_xor(rmax[reg], d, 64));
        // online softmax update
        float fac[4];
        bool need = false;
#pragma unroll
        for (int reg = 0; reg < 4; reg++) {
            float mo = m[reg];
            float mn = fmaxf(mo, rmax[reg]);
            fac[reg] = __expf(mo - mn);
            need = need || (mn > mo);
            m[reg] = mn;
        }
        if (__any(need)) {
#pragma unroll
            for (int reg = 0; reg < 4; reg++) l[reg] *= fac[reg];
#pragma unroll
            for (int fc = 0; fc < 32; fc++)
#pragma unroll
                for (int reg = 0; reg < 4; reg++) acc[fc][reg] *= fac[reg];
        }
        float rsum[4] = {0.f, 0.f, 0.f, 0.f};
#pragma unroll
        for (int fs = 0; fs < 4; fs++)
#pragma unroll
            for (int reg = 0; reg < 4; reg++) {
                float p = __expf(lgt[fs][reg] - m[reg]);
                rsum[reg] += p;
                p_lds[wid][4 * lg + reg][fs * 16 + lr] = f2bf(p);
            }
#pragma unroll
        for (int d = 1; d < 16; d <<= 1)
#pragma unroll
            for (int reg = 0; reg < 4; reg++)
                rsum[reg] += __shfl_xor(rsum[reg], d, 64);
#pragma unroll
        for (int reg = 0; reg < 4; reg++) l[reg] += rsum[reg];
        // PV: acc[t,c] += P[t,s] * vv[c,s]
        const u16* vrow = vv + ((size_t)b * CQ + lr) * TT + s0 + lg * 8;
#pragma unroll
        for (int ks = 0; ks < 2; ks++) {
            bf16x8 pf = *(const bf16x8*)&p_lds[wid][lr][ks * 32 + lg * 8];
#pragma unroll
            for (int fc = 0; fc < 32; fc++) {
                bf16x8 vf = *(const bf16x8*)(vrow + (size_t)fc * 16 * TT + ks * 32);
                acc[fc] = __builtin_amdgcn_mfma_f32_16x16x32_bf16(pf, vf, acc[fc], 0, 0, 0);
            }
        }
    }
    float inv[4];
#pragma unroll
    for (int reg = 0; reg < 4; reg++) inv[reg] = 1.f / l[reg];
#pragma unroll
    for (int fc = 0; fc < 32; fc++)
#pragma unroll
        for (int reg = 0; reg < 4; reg++) {
            int t = t0 + 4 * lg + reg;
            int c = fc * 16 + lr;
            aT[((size_t)b * TT + t) * CQ + c] = f2bf(acc[fc][reg] * inv[reg]);
        }
}

extern "C" void kernel_launch(void* const* d_in, const int* in_sizes, int n_in,
                              void* d_out, int out_size, void* d_ws, size_t ws_size,
                              hipStream_t stream) {
    const float* key_feat = (const float*)d_in[0];
    const float* query    = (const float*)d_in[1];
    const float* WM       = (const float*)d_in[2];
    const float* kpw      = (const float*)d_in[3];
    const float* norm_w   = (const float*)d_in[4];
    const float* norm_b   = (const float*)d_in[5];
    const float* qkv_w    = (const float*)d_in[6];
    const float* qkv_b    = (const float*)d_in[7];
    const float* proj_w   = (const float*)d_in[8];
    const float* proj_b   = (const float*)d_in[9];
    float* out = (float*)d_out;
    char* ws = (char*)d_ws;

    u16* kdsT = (u16*)(ws);                 //  8,388,608 B (dead after G1)
    u16* kraw = (u16*)(ws + 8388608);       // 16,777,216 B (dead after knT)
    u16* qnT  = (u16*)(ws + 25165824);
    u16* knT  = (u16*)(ws + 41943040);
    u16* qqT  = (u16*)(ws + 58720256);
    u16* kkT  = (u16*)(ws + 75497472);
    u16* vvp  = (u16*)(ws + 92274688);
    u16* aT   = (u16*)(ws);                 // reuse kdsT+kraw region (25 MB >= 16.8 MB)
    float* qsc = (float*)(ws + 109051904);
    float* qsh = qsc + NB * CQ;
    float* ksc = qsh + NB * CQ;
    float* ksh = ksc + NB * CQ;

    // 1. pool + transpose
    pool_tr_kernel<<<dim3(64, NB), 256, 0, stream>>>(key_feat, kdsT);
    // 2. k_raw = key_proj_w @ kds
    gemm_wx_kernel<0, 0><<<dim3(8, 32, NB), 256, 0, stream>>>(
        kpw, kdsT, nullptr, CK, nullptr, kraw, nullptr, nullptr, nullptr, nullptr);
    // 3. group-norm stats
    gn_stats_kernel<0><<<dim3(32, NB), 256, 0, stream>>>(query, norm_w, norm_b, qsc, qsh);
    gn_stats_kernel<1><<<dim3(32, NB), 256, 0, stream>>>(kraw, norm_w, norm_b, ksc, ksh);
    // 4. normalized, transposed activations
    affine_tr_kernel<0><<<dim3(64, 8, NB), 256, 0, stream>>>(query, qsc, qsh, qnT);
    affine_tr_kernel<1><<<dim3(64, 8, NB), 256, 0, stream>>>(kraw, ksc, ksh, knT);
    // 5. qkv projection: qq/kk transposed+scaled, vv natural
    gemm_qk_tr_kernel<<<dim3(32, 16, NB), 256, 0, stream>>>(qnT, knT, qkv_w, qkv_b, qqT, kkT);
    gemm_wx_kernel<1, 1><<<dim3(8, 32, NB), 256, 0, stream>>>(
        qkv_w + (size_t)1024 * 1024, qnT, knT, 1024, qkv_b + 1024, vvp, nullptr, nullptr, nullptr, nullptr);
    // 6. flash attention
    flash_kernel<<<dim3(64, NB), 256, 0, stream>>>(qqT, kkT, vvp, WM, aT);
    // 7. out = GN(query) + proj_w @ a + proj_b
    gemm_wx_kernel<2, 0><<<dim3(8, 32, NB), 256, 0, stream>>>(
        proj_w, aT, nullptr, CQ, proj_b, nullptr, out, query, qsc, qsh);
}

// Round 2
// 1954.297 us; speedup vs baseline: 1.2144x; 1.2144x over previous
//
#include <hip/hip_runtime.h>
#include <hip/hip_bf16.h>
#include <stdint.h>

#define NB 4
#define CQ 512
#define CK 256
#define TT 4096
#define NCH 2
#define SCH (TT / NCH)
#define SCALE_QK 0.21022410381342863f  // 512^-0.25

using bf16x8 = __attribute__((ext_vector_type(8))) short;
using f32x4  = __attribute__((ext_vector_type(4))) float;
using u32x4  = __attribute__((ext_vector_type(4))) unsigned int;
typedef unsigned short u16;

__device__ __forceinline__ u16 f2bf(float f) {
    union { float f; unsigned u; } v; v.f = f;
    return (u16)((v.u + 0x7fffu + ((v.u >> 16) & 1u)) >> 16);
}
__device__ __forceinline__ float bf2f(u16 h) {
    union { float f; unsigned u; } v; v.u = ((unsigned)h) << 16;
    return v.f;
}
__device__ __forceinline__ bf16x8 pack8(f32x4 a, f32x4 b) {
    bf16x8 r;
    r[0] = (short)f2bf(a[0]); r[1] = (short)f2bf(a[1]);
    r[2] = (short)f2bf(a[2]); r[3] = (short)f2bf(a[3]);
    r[4] = (short)f2bf(b[0]); r[5] = (short)f2bf(b[1]);
    r[6] = (short)f2bf(b[2]); r[7] = (short)f2bf(b[3]);
    return r;
}

// ---- 2x2 avg pool of key_feat (b,256,128,128) -> kdsT (b,4096,256) bf16 ----
__global__ __launch_bounds__(256) void pool_tr_kernel(const float* __restrict__ kf,
                                                      u16* __restrict__ kdsT) {
    int h = blockIdx.x, b = blockIdx.y;
    __shared__ u16 tile[64][264];  // [w][c], padded
    for (int idx = threadIdx.x; idx < 64 * 256; idx += 256) {
        int w = idx & 63, c = idx >> 6;
        const float* base = kf + (((size_t)b * CK + c) * 128 + 2 * h) * 128 + 2 * w;
        float2 r0 = *(const float2*)base;
        float2 r1 = *(const float2*)(base + 128);
        tile[w][c] = f2bf(0.25f * (r0.x + r0.y + r1.x + r1.y));
    }
    __syncthreads();
    for (int idx = threadIdx.x; idx < 64 * 32; idx += 256) {
        int w = idx >> 5, cg = (idx & 31) << 3;
        *(u32x4*)(kdsT + ((size_t)b * TT + h * 64 + w) * CK + cg) = *(const u32x4*)&tile[w][cg];
    }
}

// ---- GroupNorm stats -> per-channel scale/shift (folded affine) ----
template <int ISBF>
__global__ __launch_bounds__(256) void gn_stats_kernel(const void* __restrict__ xv,
        const float* __restrict__ gw, const float* __restrict__ gb,
        float* __restrict__ sc, float* __restrict__ sh) {
    int g = blockIdx.x, b = blockIdx.y;
    size_t base = ((size_t)b * CQ + g * 16) * TT;
    float s = 0.f, q = 0.f;
    for (int i = threadIdx.x * 4; i < 16 * TT; i += 256 * 4) {
        float v0, v1, v2, v3;
        if constexpr (ISBF) {
            const u16* x = (const u16*)xv;
            uint2 u = *(const uint2*)(x + base + i);
            v0 = bf2f((u16)(u.x & 0xffff)); v1 = bf2f((u16)(u.x >> 16));
            v2 = bf2f((u16)(u.y & 0xffff)); v3 = bf2f((u16)(u.y >> 16));
        } else {
            const float* x = (const float*)xv;
            f32x4 v = *(const f32x4*)(x + base + i);
            v0 = v[0]; v1 = v[1]; v2 = v[2]; v3 = v[3];
        }
        s += v0 + v1 + v2 + v3;
        q += v0 * v0 + v1 * v1 + v2 * v2 + v3 * v3;
    }
#pragma unroll
    for (int d = 1; d < 64; d <<= 1) { s += __shfl_xor(s, d, 64); q += __shfl_xor(q, d, 64); }
    __shared__ float shs[4], shq[4];
    int wid = threadIdx.x >> 6;
    if ((threadIdx.x & 63) == 0) { shs[wid] = s; shq[wid] = q; }
    __syncthreads();
    if (threadIdx.x < 16) {
        float S = shs[0] + shs[1] + shs[2] + shs[3];
        float Q = shq[0] + shq[1] + shq[2] + shq[3];
        const float inv = 1.f / (16.f * TT);
        float mean = S * inv, var = Q * inv - mean * mean;
        float rstd = rsqrtf(var + 1e-5f);
        int c = g * 16 + threadIdx.x;
        float w = gw[c] * rstd;
        sc[b * CQ + c] = w;
        sh[b * CQ + c] = gb[c] - mean * w;
    }
}

// ---- affine + transpose: in (b,512,T) -> out (b,T,512) bf16 ----
template <int ISBF>
__global__ __launch_bounds__(256) void affine_tr_kernel(const void* __restrict__ xv,
        const float* __restrict__ sc, const float* __restrict__ sh, u16* __restrict__ out) {
    int t0 = blockIdx.x * 64, c0 = blockIdx.y * 64, b = blockIdx.z;
    __shared__ u16 tile[64][72];  // [t][c]
    for (int idx = threadIdx.x; idx < 64 * 64; idx += 256) {
        int tl = idx & 63, cl = idx >> 6;
        int c = c0 + cl;
        float v;
        if constexpr (ISBF) v = bf2f(((const u16*)xv)[((size_t)b * CQ + c) * TT + t0 + tl]);
        else                v = ((const float*)xv)[((size_t)b * CQ + c) * TT + t0 + tl];
        tile[tl][cl] = f2bf(v * sc[b * CQ + c] + sh[b * CQ + c]);
    }
    __syncthreads();
    for (int idx = threadIdx.x; idx < 64 * 8; idx += 256) {
        int tl = idx >> 3, cg = (idx & 7) << 3;
        *(u32x4*)(out + ((size_t)b * TT + t0 + tl) * CQ + c0 + cg) = *(const u32x4*)&tile[tl][cg];
    }
}

// ---- GEMM: out[b,o,t] = sum_c W[o,c] * XT[b,t,c]  (natural-orientation) ----
// EPI 0: store bf16 (k_raw). EPI 1: +bias, store bf16 (vv). EPI 2: +bias+GN(query) residual, f32.
template <int EPI, int CONCAT>
__global__ __launch_bounds__(256) void gemm_wx_kernel(
        const float* __restrict__ W, const u16* __restrict__ X1, const u16* __restrict__ X2,
        int Ktot, const float* __restrict__ bias,
        u16* __restrict__ outb, float* __restrict__ outf,
        const float* __restrict__ query, const float* __restrict__ qsc,
        const float* __restrict__ qsh) {
    int b = blockIdx.z;
    int o_blk = blockIdx.x * 64, t_blk = blockIdx.y * 128;
    int wid = threadIdx.x >> 6, lane = threadIdx.x & 63;
    int lr = lane & 15, lg = lane >> 4;
    int o_base = o_blk + (wid >> 1) * 32;
    int t_base = t_blk + (wid & 1) * 64;
    f32x4 acc[2][4];
#pragma unroll
    for (int i = 0; i < 2; i++)
#pragma unroll
        for (int j = 0; j < 4; j++) acc[i][j] = f32x4{0.f, 0.f, 0.f, 0.f};
    int nk = Ktot >> 5;
    for (int kc = 0; kc < nk; kc++) {
        int c0 = (kc << 5) + lg * 8;
        bf16x8 am[2];
#pragma unroll
        for (int mi = 0; mi < 2; mi++) {
            const float* wp = W + (size_t)(o_base + mi * 16 + lr) * Ktot + c0;
            am[mi] = pack8(*(const f32x4*)wp, *(const f32x4*)(wp + 4));
        }
        bf16x8 bn[4];
#pragma unroll
        for (int ni = 0; ni < 4; ni++) {
            int t = t_base + ni * 16 + lr;
            const u16* xp;
            if (CONCAT) {
                xp = (c0 < 512) ? (X1 + ((size_t)b * TT + t) * 512 + c0)
                                : (X2 + ((size_t)b * TT + t) * 512 + (c0 - 512));
            } else {
                xp = X1 + ((size_t)b * TT + t) * Ktot + c0;
            }
            bn[ni] = *(const bf16x8*)xp;
        }
#pragma unroll
        for (int mi = 0; mi < 2; mi++)
#pragma unroll
            for (int ni = 0; ni < 4; ni++)
                acc[mi][ni] = __builtin_amdgcn_mfma_f32_16x16x32_bf16(am[mi], bn[ni], acc[mi][ni], 0, 0, 0);
    }
#pragma unroll
    for (int mi = 0; mi < 2; mi++) {
#pragma unroll
        for (int reg = 0; reg < 4; reg++) {
            int o = o_base + mi * 16 + 4 * lg + reg;
            float bv = (EPI >= 1) ? bias[o] : 0.f;
#pragma unroll
            for (int ni = 0; ni < 4; ni++) {
                int t = t_base + ni * 16 + lr;
                size_t oidx = ((size_t)b * CQ + o) * TT + t;
                float v = acc[mi][ni][reg] + bv;
                if (EPI == 2) {
                    outf[oidx] = v + query[oidx] * qsc[b * CQ + o] + qsh[b * CQ + o];
                } else {
                    outb[oidx] = f2bf(v);
                }
            }
        }
    }
}

// ---- swapped GEMM for qq/kk: D[b,t,o] = sum_c XT[b,t,c]*W[o,c]; store transposed layouts ----
__global__ __launch_bounds__(256) void gemm_qk_tr_kernel(
        const u16* __restrict__ qnT, const u16* __restrict__ knT,
        const float* __restrict__ W, const float* __restrict__ bias,
        u16* __restrict__ qqT, u16* __restrict__ kkT) {
    int b = blockIdx.z;
    int t_blk = blockIdx.x * 128, o_blk = blockIdx.y * 64;
    int wid = threadIdx.x >> 6, lane = threadIdx.x & 63;
    int lr = lane & 15, lg = lane >> 4;
    int t_base = t_blk + (wid >> 1) * 64;
    int o_base = o_blk + (wid & 1) * 32;
    f32x4 acc[4][2];
#pragma unroll
    for (int i = 0; i < 4; i++)
#pragma unroll
        for (int j = 0; j < 2; j++) acc[i][j] = f32x4{0.f, 0.f, 0.f, 0.f};
    for (int kc = 0; kc < 32; kc++) {
        int c0 = (kc << 5) + lg * 8;
        const u16* xb = (c0 < 512) ? qnT : knT;
        int cc = (c0 < 512) ? c0 : c0 - 512;
        bf16x8 am[4];
#pragma unroll
        for (int mi = 0; mi < 4; mi++)
            am[mi] = *(const bf16x8*)(xb + ((size_t)b * TT + t_base + mi * 16 + lr) * 512 + cc);
        bf16x8 bn[2];
#pragma unroll
        for (int ni = 0; ni < 2; ni++) {
            const float* wp = W + (size_t)(o_base + ni * 16 + lr) * 1024 + c0;
            bn[ni] = pack8(*(const f32x4*)wp, *(const f32x4*)(wp + 4));
        }
#pragma unroll
        for (int mi = 0; mi < 4; mi++)
#pragma unroll
            for (int ni = 0; ni < 2; ni++)
                acc[mi][ni] = __builtin_amdgcn_mfma_f32_16x16x32_bf16(am[mi], bn[ni], acc[mi][ni], 0, 0, 0);
    }
#pragma unroll
    for (int mi = 0; mi < 4; mi++)
#pragma unroll
        for (int ni = 0; ni < 2; ni++)
#pragma unroll
            for (int reg = 0; reg < 4; reg++) {
                int t = t_base + mi * 16 + 4 * lg + reg;
                int o = o_base + ni * 16 + lr;
                float v = (acc[mi][ni][reg] + bias[o]) * SCALE_QK;
                if (o < 512) qqT[((size_t)b * TT + t) * 512 + o] = f2bf(v);
                else         kkT[((size_t)b * TT + t) * 512 + (o - 512)] = f2bf(v);
            }
}

// ---- flash attention (split-KV): each block does 64 t-rows x one s-chunk ----
// Writes per-chunk-normalized partials: pacc bf16 [(ch*NB+b)][t][c], pm/pl f32 [(ch*NB+b)][t]
__global__ __launch_bounds__(256, 2) void flash_kernel(
        const u16* __restrict__ qqT, const u16* __restrict__ kkT, const u16* __restrict__ vv,
        const float* __restrict__ WM, u16* __restrict__ pacc,
        float* __restrict__ pm, float* __restrict__ pl) {
    int b = blockIdx.z, ch = blockIdx.y;
    int wid = threadIdx.x >> 6, lane = threadIdx.x & 63;
    int lr = lane & 15, lg = lane >> 4;
    int t0 = blockIdx.x * 64 + wid * 16;  // wave's 16 t-rows
    int sbeg = ch * SCH, send = sbeg + SCH;
    __shared__ u16 p_lds[4][16][72];      // wave-private P tile [t][s]
    bf16x8 qf[16];
    {
        const u16* qrow = qqT + ((size_t)b * TT + t0 + lr) * CQ + lg * 8;
#pragma unroll
        for (int kc = 0; kc < 16; kc++) qf[kc] = *(const bf16x8*)(qrow + kc * 32);
    }
    f32x4 acc[32];
#pragma unroll
    for (int i = 0; i < 32; i++) acc[i] = f32x4{0.f, 0.f, 0.f, 0.f};
    float m[4], l[4];
#pragma unroll
    for (int r = 0; r < 4; r++) { m[r] = -1e30f; l[r] = 0.f; }

    // register prefetch buffer for WM tile (16 values per lane)
    const float* wmbase = WM + ((size_t)b * TT + t0 + 4 * lg) * TT + lr;
    float wmbuf[16];
#pragma unroll
    for (int fs = 0; fs < 4; fs++)
#pragma unroll
        for (int reg = 0; reg < 4; reg++)
            wmbuf[fs * 4 + reg] = wmbase[(size_t)reg * TT + sbeg + fs * 16];

    for (int s0 = sbeg; s0 < send; s0 += 64) {
        // S = Q^T K for 16t x 64s
        f32x4 sacc[4];
#pragma unroll
        for (int fs = 0; fs < 4; fs++) sacc[fs] = f32x4{0.f, 0.f, 0.f, 0.f};
        const u16* krow = kkT + ((size_t)b * TT + s0 + lr) * CQ + lg * 8;
#pragma unroll
        for (int kc = 0; kc < 16; kc++) {
#pragma unroll
            for (int fs = 0; fs < 4; fs++) {
                bf16x8 kfr = *(const bf16x8*)(krow + (size_t)fs * 16 * CQ + kc * 32);
                sacc[fs] = __builtin_amdgcn_mfma_f32_16x16x32_bf16(qf[kc], kfr, sacc[fs], 0, 0, 0);
            }
        }
        // logits = WM * S ; row max
        float lgt[4][4];
        float rmax[4];
#pragma unroll
        for (int r = 0; r < 4; r++) rmax[r] = -1e30f;
#pragma unroll
        for (int fs = 0; fs < 4; fs++)
#pragma unroll
            for (int reg = 0; reg < 4; reg++) {
                float v = sacc[fs][reg] * wmbuf[fs * 4 + reg];
                lgt[fs][reg] = v;
                rmax[reg] = fmaxf(rmax[reg], v);
            }
        // prefetch next s-block's WM tile (hides HBM latency under PV + next QK MFMAs)
        {
            int s1 = (s0 + 64 < send) ? s0 + 64 : sbeg;
            float wmn[16];
#pragma unroll
            for (int fs = 0; fs < 4; fs++)
#pragma unroll
                for (int reg = 0; reg < 4; reg++)
                    wmn[fs * 4 + reg] = wmbase[(size_t)reg * TT + s1 + fs * 16];
#pragma unroll
            for (int fs = 0; fs < 4; fs++)
#pragma unroll
                for (int reg = 0; reg < 4; reg++) {
                    float tmp = wmn[fs * 4 + reg];
                    // delay overwrite until after consumption above (already consumed)
                    wmbuf[fs * 4 + reg] = tmp;
                }
        }
#pragma unroll
        for (int d = 1; d < 16; d <<= 1)
#pragma unroll
            for (int reg = 0; reg < 4; reg++)
                rmax[reg] = fmaxf(rmax[reg], __shfl_xor(rmax[reg], d, 64));
        // online softmax update
        float fac[4];
        bool need = false;
#pragma unroll
        for (int reg = 0; reg < 4; reg++) {
            float mo = m[reg];
            float mn = fmaxf(mo, rmax[reg]);
            fac[reg] = __expf(mo - mn);
            need = need || (mn > mo);
            m[reg] = mn;
        }
        if (__any(need)) {
#pragma unroll
            for (int reg = 0; reg < 4; reg++) l[reg] *= fac[reg];
#pragma unroll
            for (int fc = 0; fc < 32; fc++)
#pragma unroll
                for (int reg = 0; reg < 4; reg++) acc[fc][reg] *= fac[reg];
        }
        float rsum[4] = {0.f, 0.f, 0.f, 0.f};
#pragma unroll
        for (int fs = 0; fs < 4; fs++)
#pragma unroll
            for (int reg = 0; reg < 4; reg++) {
                float p = __expf(lgt[fs][reg] - m[reg]);
                rsum[reg] += p;
                p_lds[wid][4 * lg + reg][fs * 16 + lr] = f2bf(p);
            }
#pragma unroll
        for (int d = 1; d < 16; d <<= 1)
#pragma unroll
            for (int reg = 0; reg < 4; reg++)
                rsum[reg] += __shfl_xor(rsum[reg], d, 64);
#pragma unroll
        for (int reg = 0; reg < 4; reg++) l[reg] += rsum[reg];
        // PV: acc[t,c] += P[t,s] * vv[c,s]
        const u16* vrow = vv + ((size_t)b * CQ + lr) * TT + s0 + lg * 8;
#pragma unroll
        for (int ks = 0; ks < 2; ks++) {
            bf16x8 pf = *(const bf16x8*)&p_lds[wid][lr][ks * 32 + lg * 8];
#pragma unroll
            for (int fc = 0; fc < 32; fc++) {
                bf16x8 vf = *(const bf16x8*)(vrow + (size_t)fc * 16 * TT + ks * 32);
                acc[fc] = __builtin_amdgcn_mfma_f32_16x16x32_bf16(pf, vf, acc[fc], 0, 0, 0);
            }
        }
    }
    float inv[4];
#pragma unroll
    for (int reg = 0; reg < 4; reg++) inv[reg] = 1.f / l[reg];
    size_t row = (size_t)(ch * NB + b) * TT;
#pragma unroll
    for (int fc = 0; fc < 32; fc++)
#pragma unroll
        for (int reg = 0; reg < 4; reg++) {
            int t = t0 + 4 * lg + reg;
            int c = fc * 16 + lr;
            pacc[(row + t) * CQ + c] = f2bf(acc[fc][reg] * inv[reg]);
        }
    if (lr == 0) {
#pragma unroll
        for (int reg = 0; reg < 4; reg++) {
            int t = t0 + 4 * lg + reg;
            pm[row + t] = m[reg];
            pl[row + t] = l[reg];
        }
    }
}

// ---- combine split-KV partials: aT[b][t][c] = sum_ch w_ch * pacc_ch ----
__global__ __launch_bounds__(256) void combine_kernel(
        const u16* __restrict__ pacc, const float* __restrict__ pm,
        const float* __restrict__ pl, u16* __restrict__ aT) {
    int b = blockIdx.y;
    int t = blockIdx.x * 4 + (threadIdx.x >> 6);
    int cg = (threadIdx.x & 63) * 8;
    size_t r0 = (size_t)(0 * NB + b) * TT + t;
    size_t r1 = (size_t)(1 * NB + b) * TT + t;
    float m0 = pm[r0], m1 = pm[r1];
    float l0 = pl[r0], l1 = pl[r1];
    float M = fmaxf(m0, m1);
    float w0 = l0 * __expf(m0 - M), w1 = l1 * __expf(m1 - M);
    float inv = 1.f / (w0 + w1);
    w0 *= inv; w1 *= inv;
    bf16x8 a0 = *(const bf16x8*)(pacc + r0 * CQ + cg);
    bf16x8 a1 = *(const bf16x8*)(pacc + r1 * CQ + cg);
    bf16x8 o;
#pragma unroll
    for (int j = 0; j < 8; j++)
        o[j] = (short)f2bf(bf2f((u16)a0[j]) * w0 + bf2f((u16)a1[j]) * w1);
    *(bf16x8*)(aT + ((size_t)b * TT + t) * CQ + cg) = o;
}

extern "C" void kernel_launch(void* const* d_in, const int* in_sizes, int n_in,
                              void* d_out, int out_size, void* d_ws, size_t ws_size,
                              hipStream_t stream) {
    const float* key_feat = (const float*)d_in[0];
    const float* query    = (const float*)d_in[1];
    const float* WM       = (const float*)d_in[2];
    const float* kpw      = (const float*)d_in[3];
    const float* norm_w   = (const float*)d_in[4];
    const float* norm_b   = (const float*)d_in[5];
    const float* qkv_w    = (const float*)d_in[6];
    const float* qkv_b    = (const float*)d_in[7];
    const float* proj_w   = (const float*)d_in[8];
    const float* proj_b   = (const float*)d_in[9];
    float* out = (float*)d_out;
    char* ws = (char*)d_ws;

    u16* kdsT = (u16*)(ws);                 //  8,388,608 B (dead after G1)
    u16* kraw = (u16*)(ws + 8388608);       // 16,777,216 B (dead after knT)
    u16* qnT  = (u16*)(ws + 25165824);      // 16.8 MB (dead after vv/qk gemms)
    u16* knT  = (u16*)(ws + 41943040);      // 16.8 MB (dead after vv/qk gemms)
    u16* pacc = (u16*)(ws + 25165824);      // 33.5 MB, overlays qnT+knT (dead by flash)
    u16* qqT  = (u16*)(ws + 58720256);
    u16* kkT  = (u16*)(ws + 75497472);
    u16* vvp  = (u16*)(ws + 92274688);
    u16* aT   = (u16*)(ws);                 // reuse kdsT+kraw region (25 MB >= 16.8 MB)
    float* qsc = (float*)(ws + 109051904);
    float* qsh = qsc + NB * CQ;
    float* ksc = qsh + NB * CQ;
    float* ksh = ksc + NB * CQ;
    float* pm  = (float*)(ws + 109051904 + 32768);   // NCH*NB*TT f32 = 128 KB
    float* pl  = pm + (size_t)NCH * NB * TT;         // 128 KB

    // 1. pool + transpose
    pool_tr_kernel<<<dim3(64, NB), 256, 0, stream>>>(key_feat, kdsT);
    // 2. k_raw = key_proj_w @ kds
    gemm_wx_kernel<0, 0><<<dim3(8, 32, NB), 256, 0, stream>>>(
        kpw, kdsT, nullptr, CK, nullptr, kraw, nullptr, nullptr, nullptr, nullptr);
    // 3. group-norm stats
    gn_stats_kernel<0><<<dim3(32, NB), 256, 0, stream>>>(query, norm_w, norm_b, qsc, qsh);
    gn_stats_kernel<1><<<dim3(32, NB), 256, 0, stream>>>(kraw, norm_w, norm_b, ksc, ksh);
    // 4. normalized, transposed activations
    affine_tr_kernel<0><<<dim3(64, 8, NB), 256, 0, stream>>>(query, qsc, qsh, qnT);
    affine_tr_kernel<1><<<dim3(64, 8, NB), 256, 0, stream>>>(kraw, ksc, ksh, knT);
    // 5. qkv projection: qq/kk transposed+scaled, vv natural
    gemm_qk_tr_kernel<<<dim3(32, 16, NB), 256, 0, stream>>>(qnT, knT, qkv_w, qkv_b, qqT, kkT);
    gemm_wx_kernel<1, 1><<<dim3(8, 32, NB), 256, 0, stream>>>(
        qkv_w + (size_t)1024 * 1024, qnT, knT, 1024, qkv_b + 1024, vvp, nullptr, nullptr, nullptr, nullptr);
    // 6. flash attention, split-KV over NCH s-chunks
    flash_kernel<<<dim3(64, NCH, NB), 256, 0, stream>>>(qqT, kkT, vvp, WM, pacc, pm, pl);
    combine_kernel<<<dim3(TT / 4, NB), 256, 0, stream>>>(pacc, pm, pl, aT);
    // 7. out = GN(query) + proj_w @ a + proj_b
    gemm_wx_kernel<2, 0><<<dim3(8, 32, NB), 256, 0, stream>>>(
        proj_w, aT, nullptr, CQ, proj_b, nullptr, out, query, qsc, qsh);
}

// Round 3
// 1853.859 us; speedup vs baseline: 1.2802x; 1.0542x over previous
//
#include <hip/hip_runtime.h>
#include <hip/hip_bf16.h>
#include <stdint.h>

#define NB 4
#define CQ 512
#define CK 256
#define TT 4096
#define NCH 2
#define SCH (TT / NCH)
#define SCALE_QK 0.21022410381342863f  // 512^-0.25

using bf16x8 = __attribute__((ext_vector_type(8))) short;
using f32x4  = __attribute__((ext_vector_type(4))) float;
using u32x4  = __attribute__((ext_vector_type(4))) unsigned int;
typedef unsigned short u16;

__device__ __forceinline__ u16 f2bf(float f) {
    union { float f; unsigned u; } v; v.f = f;
    return (u16)((v.u + 0x7fffu + ((v.u >> 16) & 1u)) >> 16);
}
__device__ __forceinline__ float bf2f(u16 h) {
    union { float f; unsigned u; } v; v.u = ((unsigned)h) << 16;
    return v.f;
}
__device__ __forceinline__ bf16x8 pack8(f32x4 a, f32x4 b) {
    bf16x8 r;
    r[0] = (short)f2bf(a[0]); r[1] = (short)f2bf(a[1]);
    r[2] = (short)f2bf(a[2]); r[3] = (short)f2bf(a[3]);
    r[4] = (short)f2bf(b[0]); r[5] = (short)f2bf(b[1]);
    r[6] = (short)f2bf(b[2]); r[7] = (short)f2bf(b[3]);
    return r;
}

// ---- 2x2 avg pool of key_feat (b,256,128,128) -> kdsT (b,4096,256) bf16 ----
__global__ __launch_bounds__(256) void pool_tr_kernel(const float* __restrict__ kf,
                                                      u16* __restrict__ kdsT) {
    int h = blockIdx.x, b = blockIdx.y;
    __shared__ u16 tile[64][264];  // [w][c], padded
    for (int idx = threadIdx.x; idx < 64 * 256; idx += 256) {
        int w = idx & 63, c = idx >> 6;
        const float* base = kf + (((size_t)b * CK + c) * 128 + 2 * h) * 128 + 2 * w;
        float2 r0 = *(const float2*)base;
        float2 r1 = *(const float2*)(base + 128);
        tile[w][c] = f2bf(0.25f * (r0.x + r0.y + r1.x + r1.y));
    }
    __syncthreads();
    for (int idx = threadIdx.x; idx < 64 * 32; idx += 256) {
        int w = idx >> 5, cg = (idx & 31) << 3;
        *(u32x4*)(kdsT + ((size_t)b * TT + h * 64 + w) * CK + cg) = *(const u32x4*)&tile[w][cg];
    }
}

// ---- GroupNorm stats -> per-channel scale/shift (folded affine) ----
template <int ISBF>
__global__ __launch_bounds__(256) void gn_stats_kernel(const void* __restrict__ xv,
        const float* __restrict__ gw, const float* __restrict__ gb,
        float* __restrict__ sc, float* __restrict__ sh) {
    int g = blockIdx.x, b = blockIdx.y;
    size_t base = ((size_t)b * CQ + g * 16) * TT;
    float s = 0.f, q = 0.f;
    for (int i = threadIdx.x * 4; i < 16 * TT; i += 256 * 4) {
        float v0, v1, v2, v3;
        if constexpr (ISBF) {
            const u16* x = (const u16*)xv;
            uint2 u = *(const uint2*)(x + base + i);
            v0 = bf2f((u16)(u.x & 0xffff)); v1 = bf2f((u16)(u.x >> 16));
            v2 = bf2f((u16)(u.y & 0xffff)); v3 = bf2f((u16)(u.y >> 16));
        } else {
            const float* x = (const float*)xv;
            f32x4 v = *(const f32x4*)(x + base + i);
            v0 = v[0]; v1 = v[1]; v2 = v[2]; v3 = v[3];
        }
        s += v0 + v1 + v2 + v3;
        q += v0 * v0 + v1 * v1 + v2 * v2 + v3 * v3;
    }
#pragma unroll
    for (int d = 1; d < 64; d <<= 1) { s += __shfl_xor(s, d, 64); q += __shfl_xor(q, d, 64); }
    __shared__ float shs[4], shq[4];
    int wid = threadIdx.x >> 6;
    if ((threadIdx.x & 63) == 0) { shs[wid] = s; shq[wid] = q; }
    __syncthreads();
    if (threadIdx.x < 16) {
        float S = shs[0] + shs[1] + shs[2] + shs[3];
        float Q = shq[0] + shq[1] + shq[2] + shq[3];
        const float inv = 1.f / (16.f * TT);
        float mean = S * inv, var = Q * inv - mean * mean;
        float rstd = rsqrtf(var + 1e-5f);
        int c = g * 16 + threadIdx.x;
        float w = gw[c] * rstd;
        sc[b * CQ + c] = w;
        sh[b * CQ + c] = gb[c] - mean * w;
    }
}

// ---- affine + transpose: in (b,512,T) -> out (b,T,512) bf16 ----
template <int ISBF>
__global__ __launch_bounds__(256) void affine_tr_kernel(const void* __restrict__ xv,
        const float* __restrict__ sc, const float* __restrict__ sh, u16* __restrict__ out) {
    int t0 = blockIdx.x * 64, c0 = blockIdx.y * 64, b = blockIdx.z;
    __shared__ u16 tile[64][72];  // [t][c]
    for (int idx = threadIdx.x; idx < 64 * 64; idx += 256) {
        int tl = idx & 63, cl = idx >> 6;
        int c = c0 + cl;
        float v;
        if constexpr (ISBF) v = bf2f(((const u16*)xv)[((size_t)b * CQ + c) * TT + t0 + tl]);
        else                v = ((const float*)xv)[((size_t)b * CQ + c) * TT + t0 + tl];
        tile[tl][cl] = f2bf(v * sc[b * CQ + c] + sh[b * CQ + c]);
    }
    __syncthreads();
    for (int idx = threadIdx.x; idx < 64 * 8; idx += 256) {
        int tl = idx >> 3, cg = (idx & 7) << 3;
        *(u32x4*)(out + ((size_t)b * TT + t0 + tl) * CQ + c0 + cg) = *(const u32x4*)&tile[tl][cg];
    }
}

// ---- GEMM: out[b,o,t] = sum_c W[o,c] * XT[b,t,c]  (natural-orientation) ----
// EPI 0: store bf16 (k_raw). EPI 1: +bias, store bf16 (vv). EPI 2: +bias+GN(query) residual, f32.
template <int EPI, int CONCAT>
__global__ __launch_bounds__(256) void gemm_wx_kernel(
        const float* __restrict__ W, const u16* __restrict__ X1, const u16* __restrict__ X2,
        int Ktot, const float* __restrict__ bias,
        u16* __restrict__ outb, float* __restrict__ outf,
        const float* __restrict__ query, const float* __restrict__ qsc,
        const float* __restrict__ qsh) {
    int b = blockIdx.z;
    int o_blk = blockIdx.x * 64, t_blk = blockIdx.y * 128;
    int wid = threadIdx.x >> 6, lane = threadIdx.x & 63;
    int lr = lane & 15, lg = lane >> 4;
    int o_base = o_blk + (wid >> 1) * 32;
    int t_base = t_blk + (wid & 1) * 64;
    f32x4 acc[2][4];
#pragma unroll
    for (int i = 0; i < 2; i++)
#pragma unroll
        for (int j = 0; j < 4; j++) acc[i][j] = f32x4{0.f, 0.f, 0.f, 0.f};
    int nk = Ktot >> 5;
    for (int kc = 0; kc < nk; kc++) {
        int c0 = (kc << 5) + lg * 8;
        bf16x8 am[2];
#pragma unroll
        for (int mi = 0; mi < 2; mi++) {
            const float* wp = W + (size_t)(o_base + mi * 16 + lr) * Ktot + c0;
            am[mi] = pack8(*(const f32x4*)wp, *(const f32x4*)(wp + 4));
        }
        bf16x8 bn[4];
#pragma unroll
        for (int ni = 0; ni < 4; ni++) {
            int t = t_base + ni * 16 + lr;
            const u16* xp;
            if (CONCAT) {
                xp = (c0 < 512) ? (X1 + ((size_t)b * TT + t) * 512 + c0)
                                : (X2 + ((size_t)b * TT + t) * 512 + (c0 - 512));
            } else {
                xp = X1 + ((size_t)b * TT + t) * Ktot + c0;
            }
            bn[ni] = *(const bf16x8*)xp;
        }
#pragma unroll
        for (int mi = 0; mi < 2; mi++)
#pragma unroll
            for (int ni = 0; ni < 4; ni++)
                acc[mi][ni] = __builtin_amdgcn_mfma_f32_16x16x32_bf16(am[mi], bn[ni], acc[mi][ni], 0, 0, 0);
    }
#pragma unroll
    for (int mi = 0; mi < 2; mi++) {
#pragma unroll
        for (int reg = 0; reg < 4; reg++) {
            int o = o_base + mi * 16 + 4 * lg + reg;
            float bv = (EPI >= 1) ? bias[o] : 0.f;
#pragma unroll
            for (int ni = 0; ni < 4; ni++) {
                int t = t_base + ni * 16 + lr;
                size_t oidx = ((size_t)b * CQ + o) * TT + t;
                float v = acc[mi][ni][reg] + bv;
                if (EPI == 2) {
                    outf[oidx] = v + query[oidx] * qsc[b * CQ + o] + qsh[b * CQ + o];
                } else {
                    outb[oidx] = f2bf(v);
                }
            }
        }
    }
}

// ---- swapped GEMM for qq/kk: D[b,t,o] = sum_c XT[b,t,c]*W[o,c]; store transposed layouts ----
__global__ __launch_bounds__(256) void gemm_qk_tr_kernel(
        const u16* __restrict__ qnT, const u16* __restrict__ knT,
        const float* __restrict__ W, const float* __restrict__ bias,
        u16* __restrict__ qqT, u16* __restrict__ kkT) {
    int b = blockIdx.z;
    int t_blk = blockIdx.x * 128, o_blk = blockIdx.y * 64;
    int wid = threadIdx.x >> 6, lane = threadIdx.x & 63;
    int lr = lane & 15, lg = lane >> 4;
    int t_base = t_blk + (wid >> 1) * 64;
    int o_base = o_blk + (wid & 1) * 32;
    f32x4 acc[4][2];
#pragma unroll
    for (int i = 0; i < 4; i++)
#pragma unroll
        for (int j = 0; j < 2; j++) acc[i][j] = f32x4{0.f, 0.f, 0.f, 0.f};
    for (int kc = 0; kc < 32; kc++) {
        int c0 = (kc << 5) + lg * 8;
        const u16* xb = (c0 < 512) ? qnT : knT;
        int cc = (c0 < 512) ? c0 : c0 - 512;
        bf16x8 am[4];
#pragma unroll
        for (int mi = 0; mi < 4; mi++)
            am[mi] = *(const bf16x8*)(xb + ((size_t)b * TT + t_base + mi * 16 + lr) * 512 + cc);
        bf16x8 bn[2];
#pragma unroll
        for (int ni = 0; ni < 2; ni++) {
            const float* wp = W + (size_t)(o_base + ni * 16 + lr) * 1024 + c0;
            bn[ni] = pack8(*(const f32x4*)wp, *(const f32x4*)(wp + 4));
        }
#pragma unroll
        for (int mi = 0; mi < 4; mi++)
#pragma unroll
            for (int ni = 0; ni < 2; ni++)
                acc[mi][ni] = __builtin_amdgcn_mfma_f32_16x16x32_bf16(am[mi], bn[ni], acc[mi][ni], 0, 0, 0);
    }
#pragma unroll
    for (int mi = 0; mi < 4; mi++)
#pragma unroll
        for (int ni = 0; ni < 2; ni++)
#pragma unroll
            for (int reg = 0; reg < 4; reg++) {
                int t = t_base + mi * 16 + 4 * lg + reg;
                int o = o_base + ni * 16 + lr;
                float v = (acc[mi][ni][reg] + bias[o]) * SCALE_QK;
                if (o < 512) qqT[((size_t)b * TT + t) * 512 + o] = f2bf(v);
                else         kkT[((size_t)b * TT + t) * 512 + (o - 512)] = f2bf(v);
            }
}

// ---- flash attention (split-KV): each block does 64 t-rows x one s-chunk ----
// Q fragments staged in LDS (XOR-swizzled), WM preloaded into regs at iter start.
// Writes per-chunk-normalized partials: pacc bf16 [(ch*NB+b)][t][c], pm/pl f32 [(ch*NB+b)][t]
__global__ __launch_bounds__(256, 2) void flash_kernel(
        const u16* __restrict__ qqT, const u16* __restrict__ kkT, const u16* __restrict__ vv,
        const float* __restrict__ WM, u16* __restrict__ pacc,
        float* __restrict__ pm, float* __restrict__ pl) {
    int b = blockIdx.z, ch = blockIdx.y;
    int wid = threadIdx.x >> 6, lane = threadIdx.x & 63;
    int lr = lane & 15, lg = lane >> 4;
    int t0 = blockIdx.x * 64 + wid * 16;  // wave's 16 t-rows
    int sbeg = ch * SCH, send = sbeg + SCH;
    __shared__ u16 q_lds[4][16][512];  // wave-private Q rows, XOR-swizzled in 16B chunks
    __shared__ u16 p_lds[4][16][72];   // wave-private P tile [t][s]

    // stage this wave's 16 Q rows into LDS (swizzle: byte ^= (row&7)<<4)
    {
        const u16* qrow = qqT + ((size_t)b * TT + t0 + lr) * CQ;
        char* ldsrow = (char*)&q_lds[wid][lr][0];
        int sw = (lr & 7) << 4;
#pragma unroll
        for (int k = 0; k < 16; k++) {
            int chunk = lg + 4 * k;                       // 16B chunk 0..63
            bf16x8 v = *(const bf16x8*)(qrow + chunk * 8);
            *(bf16x8*)(ldsrow + ((chunk * 16) ^ sw)) = v;
        }
    }
    // wave-private: no __syncthreads needed

    f32x4 acc[32];
#pragma unroll
    for (int i = 0; i < 32; i++) acc[i] = f32x4{0.f, 0.f, 0.f, 0.f};
    float m[4], l[4];
#pragma unroll
    for (int r = 0; r < 4; r++) { m[r] = -1e30f; l[r] = 0.f; }

    const float* wmbase = WM + ((size_t)b * TT + t0 + 4 * lg) * TT + lr;
    const char* ldsq = (const char*)&q_lds[wid][lr][0];
    int qsw = (lr & 7) << 4;

    for (int s0 = sbeg; s0 < send; s0 += 64) {
        // issue WM loads for THIS iter up front; consumed after QK (latency hidden)
        float wmv[16];
#pragma unroll
        for (int fs = 0; fs < 4; fs++)
#pragma unroll
            for (int reg = 0; reg < 4; reg++)
                wmv[fs * 4 + reg] = wmbase[(size_t)reg * TT + s0 + fs * 16];
        // S = Q^T K for 16t x 64s
        f32x4 sacc[4];
#pragma unroll
        for (int fs = 0; fs < 4; fs++) sacc[fs] = f32x4{0.f, 0.f, 0.f, 0.f};
        const u16* krow = kkT + ((size_t)b * TT + s0 + lr) * CQ + lg * 8;
#pragma unroll
        for (int kc = 0; kc < 16; kc++) {
            bf16x8 qf = *(const bf16x8*)(ldsq + ((kc * 64 + lg * 16) ^ qsw));
#pragma unroll
            for (int fs = 0; fs < 4; fs++) {
                bf16x8 kfr = *(const bf16x8*)(krow + (size_t)fs * 16 * CQ + kc * 32);
                sacc[fs] = __builtin_amdgcn_mfma_f32_16x16x32_bf16(qf, kfr, sacc[fs], 0, 0, 0);
            }
        }
        // logits = WM * S ; row max
        float rmax[4];
#pragma unroll
        for (int r = 0; r < 4; r++) rmax[r] = -1e30f;
#pragma unroll
        for (int fs = 0; fs < 4; fs++)
#pragma unroll
            for (int reg = 0; reg < 4; reg++) {
                float v = sacc[fs][reg] * wmv[fs * 4 + reg];
                sacc[fs][reg] = v;
                rmax[reg] = fmaxf(rmax[reg], v);
            }
#pragma unroll
        for (int d = 1; d < 16; d <<= 1)
#pragma unroll
            for (int reg = 0; reg < 4; reg++)
                rmax[reg] = fmaxf(rmax[reg], __shfl_xor(rmax[reg], d, 64));
        // online softmax update
        float fac[4];
        bool need = false;
#pragma unroll
        for (int reg = 0; reg < 4; reg++) {
            float mo = m[reg];
            float mn = fmaxf(mo, rmax[reg]);
            fac[reg] = __expf(mo - mn);
            need = need || (mn > mo);
            m[reg] = mn;
        }
        if (__any(need)) {
#pragma unroll
            for (int reg = 0; reg < 4; reg++) l[reg] *= fac[reg];
#pragma unroll
            for (int fc = 0; fc < 32; fc++)
#pragma unroll
                for (int reg = 0; reg < 4; reg++) acc[fc][reg] *= fac[reg];
        }
        float rsum[4] = {0.f, 0.f, 0.f, 0.f};
#pragma unroll
        for (int fs = 0; fs < 4; fs++)
#pragma unroll
            for (int reg = 0; reg < 4; reg++) {
                float p = __expf(sacc[fs][reg] - m[reg]);
                rsum[reg] += p;
                p_lds[wid][4 * lg + reg][fs * 16 + lr] = f2bf(p);
            }
#pragma unroll
        for (int d = 1; d < 16; d <<= 1)
#pragma unroll
            for (int reg = 0; reg < 4; reg++)
                rsum[reg] += __shfl_xor(rsum[reg], d, 64);
#pragma unroll
        for (int reg = 0; reg < 4; reg++) l[reg] += rsum[reg];
        // PV: acc[t,c] += P[t,s] * vv[c,s]
        const u16* vrow = vv + ((size_t)b * CQ + lr) * TT + s0 + lg * 8;
#pragma unroll
        for (int ks = 0; ks < 2; ks++) {
            bf16x8 pf = *(const bf16x8*)&p_lds[wid][lr][ks * 32 + lg * 8];
#pragma unroll
            for (int fc = 0; fc < 32; fc++) {
                bf16x8 vf = *(const bf16x8*)(vrow + (size_t)fc * 16 * TT + ks * 32);
                acc[fc] = __builtin_amdgcn_mfma_f32_16x16x32_bf16(pf, vf, acc[fc], 0, 0, 0);
            }
        }
    }
    float inv[4];
#pragma unroll
    for (int reg = 0; reg < 4; reg++) inv[reg] = 1.f / l[reg];
    size_t row = (size_t)(ch * NB + b) * TT;
#pragma unroll
    for (int fc = 0; fc < 32; fc++)
#pragma unroll
        for (int reg = 0; reg < 4; reg++) {
            int t = t0 + 4 * lg + reg;
            int c = fc * 16 + lr;
            pacc[(row + t) * CQ + c] = f2bf(acc[fc][reg] * inv[reg]);
        }
    if (lr == 0) {
#pragma unroll
        for (int reg = 0; reg < 4; reg++) {
            int t = t0 + 4 * lg + reg;
            pm[row + t] = m[reg];
            pl[row + t] = l[reg];
        }
    }
}

// ---- combine split-KV partials: aT[b][t][c] = sum_ch w_ch * pacc_ch ----
__global__ __launch_bounds__(256) void combine_kernel(
        const u16* __restrict__ pacc, const float* __restrict__ pm,
        const float* __restrict__ pl, u16* __restrict__ aT) {
    int b = blockIdx.y;
    int t = blockIdx.x * 4 + (threadIdx.x >> 6);
    int cg = (threadIdx.x & 63) * 8;
    size_t r0 = (size_t)(0 * NB + b) * TT + t;
    size_t r1 = (size_t)(1 * NB + b) * TT + t;
    float m0 = pm[r0], m1 = pm[r1];
    float l0 = pl[r0], l1 = pl[r1];
    float M = fmaxf(m0, m1);
    float w0 = l0 * __expf(m0 - M), w1 = l1 * __expf(m1 - M);
    float inv = 1.f / (w0 + w1);
    w0 *= inv; w1 *= inv;
    bf16x8 a0 = *(const bf16x8*)(pacc + r0 * CQ + cg);
    bf16x8 a1 = *(const bf16x8*)(pacc + r1 * CQ + cg);
    bf16x8 o;
#pragma unroll
    for (int j = 0; j < 8; j++)
        o[j] = (short)f2bf(bf2f((u16)a0[j]) * w0 + bf2f((u16)a1[j]) * w1);
    *(bf16x8*)(aT + ((size_t)b * TT + t) * CQ + cg) = o;
}

extern "C" void kernel_launch(void* const* d_in, const int* in_sizes, int n_in,
                              void* d_out, int out_size, void* d_ws, size_t ws_size,
                              hipStream_t stream) {
    const float* key_feat = (const float*)d_in[0];
    const float* query    = (const float*)d_in[1];
    const float* WM       = (const float*)d_in[2];
    const float* kpw      = (const float*)d_in[3];
    const float* norm_w   = (const float*)d_in[4];
    const float* norm_b   = (const float*)d_in[5];
    const float* qkv_w    = (const float*)d_in[6];
    const float* qkv_b    = (const float*)d_in[7];
    const float* proj_w   = (const float*)d_in[8];
    const float* proj_b   = (const float*)d_in[9];
    float* out = (float*)d_out;
    char* ws = (char*)d_ws;

    u16* kdsT = (u16*)(ws);                 //  8,388,608 B (dead after G1)
    u16* kraw = (u16*)(ws + 8388608);       // 16,777,216 B (dead after knT)
    u16* qnT  = (u16*)(ws + 25165824);      // 16.8 MB (dead after vv/qk gemms)
    u16* knT  = (u16*)(ws + 41943040);      // 16.8 MB (dead after vv/qk gemms)
    u16* pacc = (u16*)(ws + 25165824);      // 33.5 MB, overlays qnT+knT (dead by flash)
    u16* qqT  = (u16*)(ws + 58720256);
    u16* kkT  = (u16*)(ws + 75497472);
    u16* vvp  = (u16*)(ws + 92274688);
    u16* aT   = (u16*)(ws);                 // reuse kdsT+kraw region (25 MB >= 16.8 MB)
    float* qsc = (float*)(ws + 109051904);
    float* qsh = qsc + NB * CQ;
    float* ksc = qsh + NB * CQ;
    float* ksh = ksc + NB * CQ;
    float* pm  = (float*)(ws + 109051904 + 32768);   // NCH*NB*TT f32 = 128 KB
    float* pl  = pm + (size_t)NCH * NB * TT;         // 128 KB

    // 1. pool + transpose
    pool_tr_kernel<<<dim3(64, NB), 256, 0, stream>>>(key_feat, kdsT);
    // 2. k_raw = key_proj_w @ kds
    gemm_wx_kernel<0, 0><<<dim3(8, 32, NB), 256, 0, stream>>>(
        kpw, kdsT, nullptr, CK, nullptr, kraw, nullptr, nullptr, nullptr, nullptr);
    // 3. group-norm stats
    gn_stats_kernel<0><<<dim3(32, NB), 256, 0, stream>>>(query, norm_w, norm_b, qsc, qsh);
    gn_stats_kernel<1><<<dim3(32, NB), 256, 0, stream>>>(kraw, norm_w, norm_b, ksc, ksh);
    // 4. normalized, transposed activations
    affine_tr_kernel<0><<<dim3(64, 8, NB), 256, 0, stream>>>(query, qsc, qsh, qnT);
    affine_tr_kernel<1><<<dim3(64, 8, NB), 256, 0, stream>>>(kraw, ksc, ksh, knT);
    // 5. qkv projection: qq/kk transposed+scaled, vv natural
    gemm_qk_tr_kernel<<<dim3(32, 16, NB), 256, 0, stream>>>(qnT, knT, qkv_w, qkv_b, qqT, kkT);
    gemm_wx_kernel<1, 1><<<dim3(8, 32, NB), 256, 0, stream>>>(
        qkv_w + (size_t)1024 * 1024, qnT, knT, 1024, qkv_b + 1024, vvp, nullptr, nullptr, nullptr, nullptr);
    // 6. flash attention, split-KV over NCH s-chunks
    flash_kernel<<<dim3(64, NCH, NB), 256, 0, stream>>>(qqT, kkT, vvp, WM, pacc, pm, pl);
    combine_kernel<<<dim3(TT / 4, NB), 256, 0, stream>>>(pacc, pm, pl, aT);
    // 7. out = GN(query) + proj_w @ a + proj_b
    gemm_wx_kernel<2, 0><<<dim3(8, 32, NB), 256, 0, stream>>>(
        proj_w, aT, nullptr, CQ, proj_b, nullptr, out, query, qsc, qsh);
}

// Round 4
// 862.099 us; speedup vs baseline: 2.7529x; 2.1504x over previous
//
#include <hip/hip_runtime.h>
#include <hip/hip_bf16.h>
#include <stdint.h>

#define NB 4
#define CQ 512
#define CK 256
#define TT 4096
#define SCALE_QK 0.21022410381342863f  // 512^-0.25

using bf16x8 = __attribute__((ext_vector_type(8))) short;
using f32x4  = __attribute__((ext_vector_type(4))) float;
using u32x4  = __attribute__((ext_vector_type(4))) unsigned int;
typedef unsigned short u16;

__device__ __forceinline__ u16 f2bf(float f) {
    union { float f; unsigned u; } v; v.f = f;
    return (u16)((v.u + 0x7fffu + ((v.u >> 16) & 1u)) >> 16);
}
__device__ __forceinline__ float bf2f(u16 h) {
    union { float f; unsigned u; } v; v.u = ((unsigned)h) << 16;
    return v.f;
}
__device__ __forceinline__ bf16x8 pack8(f32x4 a, f32x4 b) {
    bf16x8 r;
    r[0] = (short)f2bf(a[0]); r[1] = (short)f2bf(a[1]);
    r[2] = (short)f2bf(a[2]); r[3] = (short)f2bf(a[3]);
    r[4] = (short)f2bf(b[0]); r[5] = (short)f2bf(b[1]);
    r[6] = (short)f2bf(b[2]); r[7] = (short)f2bf(b[3]);
    return r;
}
// async global->LDS, 16B per lane; LDS dest = wave-uniform base + lane*16
__device__ __forceinline__ void gload_lds16(const void* g, void* l) {
    __builtin_amdgcn_global_load_lds(
        (const __attribute__((address_space(1))) unsigned int*)g,
        (__attribute__((address_space(3))) unsigned int*)l, 16, 0, 0);
}

// ---- 2x2 avg pool of key_feat (b,256,128,128) -> kdsT (b,4096,256) bf16 ----
__global__ __launch_bounds__(256) void pool_tr_kernel(const float* __restrict__ kf,
                                                      u16* __restrict__ kdsT) {
    int h = blockIdx.x, b = blockIdx.y;
    __shared__ u16 tile[64][264];  // [w][c], padded
    for (int idx = threadIdx.x; idx < 64 * 256; idx += 256) {
        int w = idx & 63, c = idx >> 6;
        const float* base = kf + (((size_t)b * CK + c) * 128 + 2 * h) * 128 + 2 * w;
        float2 r0 = *(const float2*)base;
        float2 r1 = *(const float2*)(base + 128);
        tile[w][c] = f2bf(0.25f * (r0.x + r0.y + r1.x + r1.y));
    }
    __syncthreads();
    for (int idx = threadIdx.x; idx < 64 * 32; idx += 256) {
        int w = idx >> 5, cg = (idx & 31) << 3;
        *(u32x4*)(kdsT + ((size_t)b * TT + h * 64 + w) * CK + cg) = *(const u32x4*)&tile[w][cg];
    }
}

// ---- GroupNorm stats -> per-channel scale/shift (folded affine) ----
template <int ISBF>
__global__ __launch_bounds__(256) void gn_stats_kernel(const void* __restrict__ xv,
        const float* __restrict__ gw, const float* __restrict__ gb,
        float* __restrict__ sc, float* __restrict__ sh) {
    int g = blockIdx.x, b = blockIdx.y;
    size_t base = ((size_t)b * CQ + g * 16) * TT;
    float s = 0.f, q = 0.f;
    for (int i = threadIdx.x * 4; i < 16 * TT; i += 256 * 4) {
        float v0, v1, v2, v3;
        if constexpr (ISBF) {
            const u16* x = (const u16*)xv;
            uint2 u = *(const uint2*)(x + base + i);
            v0 = bf2f((u16)(u.x & 0xffff)); v1 = bf2f((u16)(u.x >> 16));
            v2 = bf2f((u16)(u.y & 0xffff)); v3 = bf2f((u16)(u.y >> 16));
        } else {
            const float* x = (const float*)xv;
            f32x4 v = *(const f32x4*)(x + base + i);
            v0 = v[0]; v1 = v[1]; v2 = v[2]; v3 = v[3];
        }
        s += v0 + v1 + v2 + v3;
        q += v0 * v0 + v1 * v1 + v2 * v2 + v3 * v3;
    }
#pragma unroll
    for (int d = 1; d < 64; d <<= 1) { s += __shfl_xor(s, d, 64); q += __shfl_xor(q, d, 64); }
    __shared__ float shs[4], shq[4];
    int wid = threadIdx.x >> 6;
    if ((threadIdx.x & 63) == 0) { shs[wid] = s; shq[wid] = q; }
    __syncthreads();
    if (threadIdx.x < 16) {
        float S = shs[0] + shs[1] + shs[2] + shs[3];
        float Q = shq[0] + shq[1] + shq[2] + shq[3];
        const float inv = 1.f / (16.f * TT);
        float mean = S * inv, var = Q * inv - mean * mean;
        float rstd = rsqrtf(var + 1e-5f);
        int c = g * 16 + threadIdx.x;
        float w = gw[c] * rstd;
        sc[b * CQ + c] = w;
        sh[b * CQ + c] = gb[c] - mean * w;
    }
}

// ---- affine + transpose: in (b,512,T) -> out (b,T,512) bf16 ----
template <int ISBF>
__global__ __launch_bounds__(256) void affine_tr_kernel(const void* __restrict__ xv,
        const float* __restrict__ sc, const float* __restrict__ sh, u16* __restrict__ out) {
    int t0 = blockIdx.x * 64, c0 = blockIdx.y * 64, b = blockIdx.z;
    __shared__ u16 tile[64][72];  // [t][c]
    for (int idx = threadIdx.x; idx < 64 * 64; idx += 256) {
        int tl = idx & 63, cl = idx >> 6;
        int c = c0 + cl;
        float v;
        if constexpr (ISBF) v = bf2f(((const u16*)xv)[((size_t)b * CQ + c) * TT + t0 + tl]);
        else                v = ((const float*)xv)[((size_t)b * CQ + c) * TT + t0 + tl];
        tile[tl][cl] = f2bf(v * sc[b * CQ + c] + sh[b * CQ + c]);
    }
    __syncthreads();
    for (int idx = threadIdx.x; idx < 64 * 8; idx += 256) {
        int tl = idx >> 3, cg = (idx & 7) << 3;
        *(u32x4*)(out + ((size_t)b * TT + t0 + tl) * CQ + c0 + cg) = *(const u32x4*)&tile[tl][cg];
    }
}

// ---- GEMM: out[b,o,t] = sum_c W[o,c] * XT[b,t,c]  (natural-orientation) ----
template <int EPI, int CONCAT>
__global__ __launch_bounds__(256) void gemm_wx_kernel(
        const float* __restrict__ W, const u16* __restrict__ X1, const u16* __restrict__ X2,
        int Ktot, const float* __restrict__ bias,
        u16* __restrict__ outb, float* __restrict__ outf,
        const float* __restrict__ query, const float* __restrict__ qsc,
        const float* __restrict__ qsh) {
    int b = blockIdx.z;
    int o_blk = blockIdx.x * 64, t_blk = blockIdx.y * 128;
    int wid = threadIdx.x >> 6, lane = threadIdx.x & 63;
    int lr = lane & 15, lg = lane >> 4;
    int o_base = o_blk + (wid >> 1) * 32;
    int t_base = t_blk + (wid & 1) * 64;
    f32x4 acc[2][4];
#pragma unroll
    for (int i = 0; i < 2; i++)
#pragma unroll
        for (int j = 0; j < 4; j++) acc[i][j] = f32x4{0.f, 0.f, 0.f, 0.f};
    int nk = Ktot >> 5;
    for (int kc = 0; kc < nk; kc++) {
        int c0 = (kc << 5) + lg * 8;
        bf16x8 am[2];
#pragma unroll
        for (int mi = 0; mi < 2; mi++) {
            const float* wp = W + (size_t)(o_base + mi * 16 + lr) * Ktot + c0;
            am[mi] = pack8(*(const f32x4*)wp, *(const f32x4*)(wp + 4));
        }
        bf16x8 bn[4];
#pragma unroll
        for (int ni = 0; ni < 4; ni++) {
            int t = t_base + ni * 16 + lr;
            const u16* xp;
            if (CONCAT) {
                xp = (c0 < 512) ? (X1 + ((size_t)b * TT + t) * 512 + c0)
                                : (X2 + ((size_t)b * TT + t) * 512 + (c0 - 512));
            } else {
                xp = X1 + ((size_t)b * TT + t) * Ktot + c0;
            }
            bn[ni] = *(const bf16x8*)xp;
        }
#pragma unroll
        for (int mi = 0; mi < 2; mi++)
#pragma unroll
            for (int ni = 0; ni < 4; ni++)
                acc[mi][ni] = __builtin_amdgcn_mfma_f32_16x16x32_bf16(am[mi], bn[ni], acc[mi][ni], 0, 0, 0);
    }
#pragma unroll
    for (int mi = 0; mi < 2; mi++) {
#pragma unroll
        for (int reg = 0; reg < 4; reg++) {
            int o = o_base + mi * 16 + 4 * lg + reg;
            float bv = (EPI >= 1) ? bias[o] : 0.f;
#pragma unroll
            for (int ni = 0; ni < 4; ni++) {
                int t = t_base + ni * 16 + lr;
                size_t oidx = ((size_t)b * CQ + o) * TT + t;
                float v = acc[mi][ni][reg] + bv;
                if (EPI == 2) {
                    outf[oidx] = v + query[oidx] * qsc[b * CQ + o] + qsh[b * CQ + o];
                } else {
                    outb[oidx] = f2bf(v);
                }
            }
        }
    }
}

// ---- swapped GEMM for qq/kk: D[b,t,o] = sum_c XT[b,t,c]*W[o,c]; store transposed layouts ----
__global__ __launch_bounds__(256) void gemm_qk_tr_kernel(
        const u16* __restrict__ qnT, const u16* __restrict__ knT,
        const float* __restrict__ W, const float* __restrict__ bias,
        u16* __restrict__ qqT, u16* __restrict__ kkT) {
    int b = blockIdx.z;
    int t_blk = blockIdx.x * 128, o_blk = blockIdx.y * 64;
    int wid = threadIdx.x >> 6, lane = threadIdx.x & 63;
    int lr = lane & 15, lg = lane >> 4;
    int t_base = t_blk + (wid >> 1) * 64;
    int o_base = o_blk + (wid & 1) * 32;
    f32x4 acc[4][2];
#pragma unroll
    for (int i = 0; i < 4; i++)
#pragma unroll
        for (int j = 0; j < 2; j++) acc[i][j] = f32x4{0.f, 0.f, 0.f, 0.f};
    for (int kc = 0; kc < 32; kc++) {
        int c0 = (kc << 5) + lg * 8;
        const u16* xb = (c0 < 512) ? qnT : knT;
        int cc = (c0 < 512) ? c0 : c0 - 512;
        bf16x8 am[4];
#pragma unroll
        for (int mi = 0; mi < 4; mi++)
            am[mi] = *(const bf16x8*)(xb + ((size_t)b * TT + t_base + mi * 16 + lr) * 512 + cc);
        bf16x8 bn[2];
#pragma unroll
        for (int ni = 0; ni < 2; ni++) {
            const float* wp = W + (size_t)(o_base + ni * 16 + lr) * 1024 + c0;
            bn[ni] = pack8(*(const f32x4*)wp, *(const f32x4*)(wp + 4));
        }
#pragma unroll
        for (int mi = 0; mi < 4; mi++)
#pragma unroll
            for (int ni = 0; ni < 2; ni++)
                acc[mi][ni] = __builtin_amdgcn_mfma_f32_16x16x32_bf16(am[mi], bn[ni], acc[mi][ni], 0, 0, 0);
    }
#pragma unroll
    for (int mi = 0; mi < 4; mi++)
#pragma unroll
        for (int ni = 0; ni < 2; ni++)
#pragma unroll
            for (int reg = 0; reg < 4; reg++) {
                int t = t_base + mi * 16 + 4 * lg + reg;
                int o = o_base + ni * 16 + lr;
                float v = (acc[mi][ni][reg] + bias[o]) * SCALE_QK;
                if (o < 512) qqT[((size_t)b * TT + t) * 512 + o] = f2bf(v);
                else         kkT[((size_t)b * TT + t) * 512 + (o - 512)] = f2bf(v);
            }
}

// ---- flash attention v4: LDS-staged K/V tiles, 8 waves, 1 block/CU ----
// Block: 64 t-rows, full s sweep. Wave (tb,sb): QK 16t x 32s; PV 16t x 256c.
__global__ __launch_bounds__(512, 2) void flash_kernel(
        const u16* __restrict__ qqT, const u16* __restrict__ kkT,
        const u16* __restrict__ vv, const float* __restrict__ WM,
        u16* __restrict__ aT) {
    int b = blockIdx.y;
    int T0 = blockIdx.x * 64;
    int wid = threadIdx.x >> 6, lane = threadIdx.x & 63;
    int lr = lane & 15, lg = lane >> 4;
    int tb = wid >> 1, sb = wid & 1;

    __shared__ u16 K_lds[64][512];   // [s][c], chunk-swizzled by (s&7)
    __shared__ u16 V_lds[512][64];   // [c][s], chunk-swizzled by (c&7)
    __shared__ u16 p_lds[64][64];    // [t][s], chunk-swizzled by (t&7)
    __shared__ float ex_max[64][2];
    __shared__ float ex_sum[64][2];

    // Q register-resident: rows T0+16tb+lr (A-frag: row=lr, k=8lg+j)
    bf16x8 qf[16];
    {
        const u16* qrow = qqT + ((size_t)b * TT + T0 + 16 * tb + lr) * CQ + lg * 8;
#pragma unroll
        for (int kc = 0; kc < 16; kc++) qf[kc] = *(const bf16x8*)(qrow + kc * 32);
    }
    f32x4 acc[16];
#pragma unroll
    for (int i = 0; i < 16; i++) acc[i] = f32x4{0.f, 0.f, 0.f, 0.f};
    float m[4], l[4];
#pragma unroll
    for (int r = 0; r < 4; r++) { m[r] = -1e30f; l[r] = 0.f; }

    const float* wmrow = WM + ((size_t)b * TT + T0 + 16 * tb + 4 * lg) * TT + 32 * sb + lr;
    const char* kbase = (const char*)(kkT + ((size_t)b * TT) * CQ);
    int myt = 16 * tb + 4 * lg;  // first of this lane's 4 t-rows (local)

    for (int s0 = 0; s0 < TT; s0 += 64) {
        __syncthreads();  // bar1: everyone done reading K/V of previous tile
        // stage K rows [wid*8, wid*8+8): 1KB each, source chunk-XOR'd by (s&7)
#pragma unroll
        for (int i = 0; i < 8; i++) {
            int s = wid * 8 + i;
            gload_lds16(kbase + ((size_t)(s0 + s)) * 1024 + ((lane ^ (s & 7)) << 4),
                        &K_lds[s][0]);
        }
        // stage V rows: 8 c-rows (128B each) per instruction
#pragma unroll
        for (int g2 = 0; g2 < 8; g2++) {
            int c0 = (wid * 8 + g2) * 8;
            int c = c0 + (lane >> 3);
            gload_lds16((const char*)(vv + ((size_t)b * CQ + c) * TT + s0) +
                            ((((lane & 7) ^ (c & 7))) << 4),
                        &V_lds[c0][0]);
        }
        // WM for this iter (coalesced 64B segments), drained by bar2 with the staging
        float wmv[2][4];
#pragma unroll
        for (int fs = 0; fs < 2; fs++)
#pragma unroll
            for (int reg = 0; reg < 4; reg++)
                wmv[fs][reg] = wmrow[(size_t)reg * TT + s0 + fs * 16];
        __syncthreads();  // bar2: K/V tiles in LDS

        // QK: S[16t x 32s]
        f32x4 sacc[2];
        sacc[0] = f32x4{0.f, 0.f, 0.f, 0.f};
        sacc[1] = f32x4{0.f, 0.f, 0.f, 0.f};
#pragma unroll
        for (int kc = 0; kc < 16; kc++) {
#pragma unroll
            for (int fs = 0; fs < 2; fs++) {
                const char* kp = (const char*)&K_lds[32 * sb + fs * 16 + lr][0];
                bf16x8 kfr = *(const bf16x8*)(kp + ((((kc << 2) | lg) ^ (lr & 7)) << 4));
                sacc[fs] = __builtin_amdgcn_mfma_f32_16x16x32_bf16(qf[kc], kfr, sacc[fs], 0, 0, 0);
            }
        }
        // logits = WM*S, partial row max over this wave's 32 s
        float lgt[2][4], pmax[4];
#pragma unroll
        for (int r = 0; r < 4; r++) pmax[r] = -3e38f;
#pragma unroll
        for (int fs = 0; fs < 2; fs++)
#pragma unroll
            for (int reg = 0; reg < 4; reg++) {
                float v = sacc[fs][reg] * wmv[fs][reg];
                lgt[fs][reg] = v;
                pmax[reg] = fmaxf(pmax[reg], v);
            }
#pragma unroll
        for (int d = 1; d < 16; d <<= 1)
#pragma unroll
            for (int reg = 0; reg < 4; reg++)
                pmax[reg] = fmaxf(pmax[reg], __shfl_xor(pmax[reg], d, 64));
        if (lr == 0) {
#pragma unroll
            for (int reg = 0; reg < 4; reg++) ex_max[myt + reg][sb] = pmax[reg];
        }
        __syncthreads();  // bar3: maxes exchanged
        float fac[4], rsum[4];
#pragma unroll
        for (int reg = 0; reg < 4; reg++) {
            int t = myt + reg;
            float mn = fmaxf(m[reg], fmaxf(ex_max[t][0], ex_max[t][1]));
            fac[reg] = __expf(m[reg] - mn);
            m[reg] = mn;
            rsum[reg] = 0.f;
        }
#pragma unroll
        for (int fs = 0; fs < 2; fs++)
#pragma unroll
            for (int reg = 0; reg < 4; reg++) {
                float p = __expf(lgt[fs][reg] - m[reg]);
                rsum[reg] += p;
                int t = myt + reg;
                int s = 32 * sb + fs * 16 + lr;
                *(u16*)((char*)p_lds + t * 128 + ((((s >> 3) ^ (t & 7))) << 4) + ((s & 7) << 1)) = f2bf(p);
            }
#pragma unroll
        for (int d = 1; d < 16; d <<= 1)
#pragma unroll
            for (int reg = 0; reg < 4; reg++)
                rsum[reg] += __shfl_xor(rsum[reg], d, 64);
        if (lr == 0) {
#pragma unroll
            for (int reg = 0; reg < 4; reg++) ex_sum[myt + reg][sb] = rsum[reg];
        }
        __syncthreads();  // bar4: P + sums ready
#pragma unroll
        for (int reg = 0; reg < 4; reg++) {
            int t = myt + reg;
            l[reg] = l[reg] * fac[reg] + ex_sum[t][0] + ex_sum[t][1];
        }
#pragma unroll
        for (int nt = 0; nt < 16; nt++)
#pragma unroll
            for (int reg = 0; reg < 4; reg++) acc[nt][reg] *= fac[reg];
        // PV: acc[16t x 256c] += P[16t x 64s] * V[256c x 64s]
#pragma unroll
        for (int ks = 0; ks < 2; ks++) {
            int prow = 16 * tb + lr;
            bf16x8 pa = *(const bf16x8*)((const char*)p_lds + prow * 128 +
                                         ((((ks << 2) | lg) ^ (lr & 7)) << 4));
#pragma unroll
            for (int nt = 0; nt < 16; nt++) {
                int vr = 256 * sb + nt * 16 + lr;
                bf16x8 vf = *(const bf16x8*)((const char*)&V_lds[vr][0] +
                                             ((((ks << 2) | lg) ^ (lr & 7)) << 4));
                acc[nt] = __builtin_amdgcn_mfma_f32_16x16x32_bf16(pa, vf, acc[nt], 0, 0, 0);
            }
        }
    }
    // epilogue: normalize + store
    float inv[4];
#pragma unroll
    for (int reg = 0; reg < 4; reg++) inv[reg] = 1.f / l[reg];
#pragma unroll
    for (int nt = 0; nt < 16; nt++)
#pragma unroll
        for (int reg = 0; reg < 4; reg++) {
            int t = T0 + myt + reg;
            int c = 256 * sb + nt * 16 + lr;
            aT[((size_t)b * TT + t) * CQ + c] = f2bf(acc[nt][reg] * inv[reg]);
        }
}

extern "C" void kernel_launch(void* const* d_in, const int* in_sizes, int n_in,
                              void* d_out, int out_size, void* d_ws, size_t ws_size,
                              hipStream_t stream) {
    const float* key_feat = (const float*)d_in[0];
    const float* query    = (const float*)d_in[1];
    const float* WM       = (const float*)d_in[2];
    const float* kpw      = (const float*)d_in[3];
    const float* norm_w   = (const float*)d_in[4];
    const float* norm_b   = (const float*)d_in[5];
    const float* qkv_w    = (const float*)d_in[6];
    const float* qkv_b    = (const float*)d_in[7];
    const float* proj_w   = (const float*)d_in[8];
    const float* proj_b   = (const float*)d_in[9];
    float* out = (float*)d_out;
    char* ws = (char*)d_ws;

    u16* kdsT = (u16*)(ws);                 //  8.4 MB (dead after gemm#2)
    u16* kraw = (u16*)(ws + 8388608);       // 16.8 MB (dead after knT)
    u16* qnT  = (u16*)(ws + 25165824);      // 16.8 MB
    u16* knT  = (u16*)(ws + 41943040);      // 16.8 MB
    u16* qqT  = (u16*)(ws + 58720256);
    u16* kkT  = (u16*)(ws + 75497472);
    u16* vvp  = (u16*)(ws + 92274688);
    u16* aT   = (u16*)(ws);                 // reuse kdsT+kraw region (dead by flash)
    float* qsc = (float*)(ws + 109051904);
    float* qsh = qsc + NB * CQ;
    float* ksc = qsh + NB * CQ;
    float* ksh = ksc + NB * CQ;

    // 1. pool + transpose
    pool_tr_kernel<<<dim3(64, NB), 256, 0, stream>>>(key_feat, kdsT);
    // 2. k_raw = key_proj_w @ kds
    gemm_wx_kernel<0, 0><<<dim3(8, 32, NB), 256, 0, stream>>>(
        kpw, kdsT, nullptr, CK, nullptr, kraw, nullptr, nullptr, nullptr, nullptr);
    // 3. group-norm stats
    gn_stats_kernel<0><<<dim3(32, NB), 256, 0, stream>>>(query, norm_w, norm_b, qsc, qsh);
    gn_stats_kernel<1><<<dim3(32, NB), 256, 0, stream>>>(kraw, norm_w, norm_b, ksc, ksh);
    // 4. normalized, transposed activations
    affine_tr_kernel<0><<<dim3(64, 8, NB), 256, 0, stream>>>(query, qsc, qsh, qnT);
    affine_tr_kernel<1><<<dim3(64, 8, NB), 256, 0, stream>>>(kraw, ksc, ksh, knT);
    // 5. qkv projection: qq/kk transposed+scaled, vv natural
    gemm_qk_tr_kernel<<<dim3(32, 16, NB), 256, 0, stream>>>(qnT, knT, qkv_w, qkv_b, qqT, kkT);
    gemm_wx_kernel<1, 1><<<dim3(8, 32, NB), 256, 0, stream>>>(
        qkv_w + (size_t)1024 * 1024, qnT, knT, 1024, qkv_b + 1024, vvp, nullptr, nullptr, nullptr, nullptr);
    // 6. flash attention (LDS-staged, 1 block/CU)
    flash_kernel<<<dim3(64, NB), 512, 0, stream>>>(qqT, kkT, vvp, WM, aT);
    // 7. out = GN(query) + proj_w @ a + proj_b
    gemm_wx_kernel<2, 0><<<dim3(8, 32, NB), 256, 0, stream>>>(
        proj_w, aT, nullptr, CQ, proj_b, nullptr, out, query, qsc, qsh);
}

// Round 5
// 543.927 us; speedup vs baseline: 4.3632x; 1.5850x over previous
//
#include <hip/hip_runtime.h>
#include <hip/hip_bf16.h>
#include <stdint.h>

#define NB 4
#define CQ 512
#define CK 256
#define TT 4096
#define SCALE_QK 0.21022410381342863f  // 512^-0.25

using bf16x8 = __attribute__((ext_vector_type(8))) short;
using f32x4  = __attribute__((ext_vector_type(4))) float;
using u32x4  = __attribute__((ext_vector_type(4))) unsigned int;
typedef unsigned short u16;

__device__ __forceinline__ u16 f2bf(float f) {
    union { float f; unsigned u; } v; v.f = f;
    return (u16)((v.u + 0x7fffu + ((v.u >> 16) & 1u)) >> 16);
}
__device__ __forceinline__ float bf2f(u16 h) {
    union { float f; unsigned u; } v; v.u = ((unsigned)h) << 16;
    return v.f;
}
__device__ __forceinline__ bf16x8 pack8(f32x4 a, f32x4 b) {
    bf16x8 r;
    r[0] = (short)f2bf(a[0]); r[1] = (short)f2bf(a[1]);
    r[2] = (short)f2bf(a[2]); r[3] = (short)f2bf(a[3]);
    r[4] = (short)f2bf(b[0]); r[5] = (short)f2bf(b[1]);
    r[6] = (short)f2bf(b[2]); r[7] = (short)f2bf(b[3]);
    return r;
}
// async global->LDS, 16B per lane; LDS dest = wave-uniform base + lane*16
__device__ __forceinline__ void gload_lds16(const void* g, void* l) {
    __builtin_amdgcn_global_load_lds(
        (const __attribute__((address_space(1))) unsigned int*)g,
        (__attribute__((address_space(3))) unsigned int*)l, 16, 0, 0);
}

// ---- weight f32 -> bf16 conversion (optionally scale first scale_until elements) ----
__global__ __launch_bounds__(256) void wconv_kernel(const float* __restrict__ src,
        u16* __restrict__ dst, int n, int scale_until) {
    int i = (blockIdx.x * 256 + threadIdx.x) * 8;
    if (i >= n) return;
    f32x4 a = *(const f32x4*)(src + i);
    f32x4 c = *(const f32x4*)(src + i + 4);
    if (i < scale_until) {
        a *= SCALE_QK;
        c *= SCALE_QK;
    }
    *(bf16x8*)(dst + i) = pack8(a, c);
}

// ---- 2x2 avg pool of key_feat (b,256,128,128) -> kdsT (b,4096,256) bf16 ----
__global__ __launch_bounds__(256) void pool_tr_kernel(const float* __restrict__ kf,
                                                      u16* __restrict__ kdsT) {
    int h = blockIdx.x, b = blockIdx.y;
    __shared__ u16 tile[64][264];  // [w][c], padded
    for (int idx = threadIdx.x; idx < 64 * 256; idx += 256) {
        int w = idx & 63, c = idx >> 6;
        const float* base = kf + (((size_t)b * CK + c) * 128 + 2 * h) * 128 + 2 * w;
        float2 r0 = *(const float2*)base;
        float2 r1 = *(const float2*)(base + 128);
        tile[w][c] = f2bf(0.25f * (r0.x + r0.y + r1.x + r1.y));
    }
    __syncthreads();
    for (int idx = threadIdx.x; idx < 64 * 32; idx += 256) {
        int w = idx >> 5, cg = (idx & 31) << 3;
        *(u32x4*)(kdsT + ((size_t)b * TT + h * 64 + w) * CK + cg) = *(const u32x4*)&tile[w][cg];
    }
}

// ---- GroupNorm stats -> per-channel scale/shift (folded affine) ----
template <int ISBF>
__global__ __launch_bounds__(256) void gn_stats_kernel(const void* __restrict__ xv,
        const float* __restrict__ gw, const float* __restrict__ gb,
        float* __restrict__ sc, float* __restrict__ sh) {
    int g = blockIdx.x, b = blockIdx.y;
    size_t base = ((size_t)b * CQ + g * 16) * TT;
    float s = 0.f, q = 0.f;
    for (int i = threadIdx.x * 4; i < 16 * TT; i += 256 * 4) {
        float v0, v1, v2, v3;
        if constexpr (ISBF) {
            const u16* x = (const u16*)xv;
            uint2 u = *(const uint2*)(x + base + i);
            v0 = bf2f((u16)(u.x & 0xffff)); v1 = bf2f((u16)(u.x >> 16));
            v2 = bf2f((u16)(u.y & 0xffff)); v3 = bf2f((u16)(u.y >> 16));
        } else {
            const float* x = (const float*)xv;
            f32x4 v = *(const f32x4*)(x + base + i);
            v0 = v[0]; v1 = v[1]; v2 = v[2]; v3 = v[3];
        }
        s += v0 + v1 + v2 + v3;
        q += v0 * v0 + v1 * v1 + v2 * v2 + v3 * v3;
    }
#pragma unroll
    for (int d = 1; d < 64; d <<= 1) { s += __shfl_xor(s, d, 64); q += __shfl_xor(q, d, 64); }
    __shared__ float shs[4], shq[4];
    int wid = threadIdx.x >> 6;
    if ((threadIdx.x & 63) == 0) { shs[wid] = s; shq[wid] = q; }
    __syncthreads();
    if (threadIdx.x < 16) {
        float S = shs[0] + shs[1] + shs[2] + shs[3];
        float Q = shq[0] + shq[1] + shq[2] + shq[3];
        const float inv = 1.f / (16.f * TT);
        float mean = S * inv, var = Q * inv - mean * mean;
        float rstd = rsqrtf(var + 1e-5f);
        int c = g * 16 + threadIdx.x;
        float w = gw[c] * rstd;
        sc[b * CQ + c] = w;
        sh[b * CQ + c] = gb[c] - mean * w;
    }
}

// ---- affine + transpose: in (b,512,T) -> out (b,T,512) bf16 ----
template <int ISBF>
__global__ __launch_bounds__(256) void affine_tr_kernel(const void* __restrict__ xv,
        const float* __restrict__ sc, const float* __restrict__ sh, u16* __restrict__ out) {
    int t0 = blockIdx.x * 64, c0 = blockIdx.y * 64, b = blockIdx.z;
    __shared__ u16 tile[64][72];  // [t][c]
    for (int idx = threadIdx.x; idx < 64 * 64; idx += 256) {
        int tl = idx & 63, cl = idx >> 6;
        int c = c0 + cl;
        float v;
        if constexpr (ISBF) v = bf2f(((const u16*)xv)[((size_t)b * CQ + c) * TT + t0 + tl]);
        else                v = ((const float*)xv)[((size_t)b * CQ + c) * TT + t0 + tl];
        tile[tl][cl] = f2bf(v * sc[b * CQ + c] + sh[b * CQ + c]);
    }
    __syncthreads();
    for (int idx = threadIdx.x; idx < 64 * 8; idx += 256) {
        int tl = idx >> 3, cg = (idx & 7) << 3;
        *(u32x4*)(out + ((size_t)b * TT + t0 + tl) * CQ + c0 + cg) = *(const u32x4*)&tile[tl][cg];
    }
}

// ---- staged GEMM: 128o x 128t tile, BK=64, double-buffered LDS, global_load_lds ----
// Wb: bf16 weights [M][Ktot]. X: bf16 [b][t][Kx] (Kx=512 if CONCAT else Ktot).
// Normal (SWAP=0): D[o][t].  EPI 0: bf16 store. 1: +bias, bf16. 2: +bias+GN(query) res, f32.
// SWAP=1 (qk): D[t][o] with o in [0,1024); v=acc+bias[o]*SCALE_QK; o<512 -> outb, else outb2.
template <int EPI, int CONCAT, int SWAP>
__global__ __launch_bounds__(256) void gemm_st_kernel(
        const u16* __restrict__ Wb, const u16* __restrict__ X1, const u16* __restrict__ X2,
        int Ktot, const float* __restrict__ bias,
        u16* __restrict__ outb, u16* __restrict__ outb2, float* __restrict__ outf,
        const float* __restrict__ query, const float* __restrict__ qsc,
        const float* __restrict__ qsh) {
    int b = blockIdx.z;
    int o0 = blockIdx.x * 128, t0 = blockIdx.y * 128;
    int wid = threadIdx.x >> 6, lane = threadIdx.x & 63;
    int lr = lane & 15, lg = lane >> 4;
    int osub = (wid >> 1) * 64, tsub = (wid & 1) * 64;

    __shared__ u16 Wl[2][128][64];  // 16KB per buf
    __shared__ u16 Xl[2][128][64];  // 16KB per buf

    const int Kx = CONCAT ? 512 : Ktot;
    int srow = lane >> 3;                       // 0..7
    int sxw = ((lane & 7) ^ srow) << 4;         // source-side XOR swizzle byte offset
    int xr = (lr & 7) << 4;                     // read-side XOR

    f32x4 acc[4][4];
#pragma unroll
    for (int i = 0; i < 4; i++)
#pragma unroll
        for (int j = 0; j < 4; j++) acc[i][j] = f32x4{0.f, 0.f, 0.f, 0.f};

    int nk = Ktot >> 6;

#define STAGE_TILE(KC, BUF)                                                          \
    do {                                                                             \
        int c0_ = (KC) << 6;                                                         \
        const u16* xs_;                                                              \
        if (CONCAT && c0_ >= 512) xs_ = X2 + ((size_t)b * TT) * 512 + (c0_ - 512);   \
        else if (CONCAT)          xs_ = X1 + ((size_t)b * TT) * 512 + c0_;           \
        else                      xs_ = X1 + ((size_t)b * TT) * (size_t)Ktot + c0_;  \
        const char* xb_ = (const char*)(xs_ + (size_t)(t0 + wid * 32) * Kx) + sxw;   \
        const char* wb_ = (const char*)(Wb + (size_t)(o0 + wid * 32) * Ktot + c0_) + sxw; \
        _Pragma("unroll")                                                            \
        for (int i_ = 0; i_ < 4; i_++) {                                             \
            gload_lds16(xb_ + (size_t)(i_ * 8 + srow) * (Kx * 2),                    \
                        &Xl[BUF][wid * 32 + i_ * 8][0]);                             \
            gload_lds16(wb_ + (size_t)(i_ * 8 + srow) * (Ktot * 2),                  \
                        &Wl[BUF][wid * 32 + i_ * 8][0]);                             \
        }                                                                            \
    } while (0)

    STAGE_TILE(0, 0);
    __syncthreads();
    int cur = 0;
    for (int kc = 0; kc < nk; kc++) {
        if (kc + 1 < nk) STAGE_TILE(kc + 1, cur ^ 1);
#pragma unroll
        for (int kk = 0; kk < 2; kk++) {
            int boff = (kk * 64 + lg * 16) ^ xr;
            bf16x8 am[4], bn[4];
#pragma unroll
            for (int mi = 0; mi < 4; mi++) {
                if (SWAP) am[mi] = *(const bf16x8*)((const char*)&Xl[cur][tsub + mi * 16 + lr][0] + boff);
                else      am[mi] = *(const bf16x8*)((const char*)&Wl[cur][osub + mi * 16 + lr][0] + boff);
            }
#pragma unroll
            for (int ni = 0; ni < 4; ni++) {
                if (SWAP) bn[ni] = *(const bf16x8*)((const char*)&Wl[cur][osub + ni * 16 + lr][0] + boff);
                else      bn[ni] = *(const bf16x8*)((const char*)&Xl[cur][tsub + ni * 16 + lr][0] + boff);
            }
#pragma unroll
            for (int mi = 0; mi < 4; mi++)
#pragma unroll
                for (int ni = 0; ni < 4; ni++)
                    acc[mi][ni] = __builtin_amdgcn_mfma_f32_16x16x32_bf16(am[mi], bn[ni], acc[mi][ni], 0, 0, 0);
        }
        __syncthreads();
        cur ^= 1;
    }
#undef STAGE_TILE

    if (SWAP) {
        // D[t][o]: row (A) = t, col (B) = o
#pragma unroll
        for (int mi = 0; mi < 4; mi++)
#pragma unroll
            for (int ni = 0; ni < 4; ni++)
#pragma unroll
                for (int reg = 0; reg < 4; reg++) {
                    int t = t0 + tsub + mi * 16 + 4 * lg + reg;
                    int o = o0 + osub + ni * 16 + lr;
                    float v = acc[mi][ni][reg] + bias[o] * SCALE_QK;
                    if (o < 512) outb[((size_t)b * TT + t) * 512 + o] = f2bf(v);
                    else         outb2[((size_t)b * TT + t) * 512 + (o - 512)] = f2bf(v);
                }
    } else {
#pragma unroll
        for (int mi = 0; mi < 4; mi++)
#pragma unroll
            for (int reg = 0; reg < 4; reg++) {
                int o = o0 + osub + mi * 16 + 4 * lg + reg;
                float bv = (EPI >= 1) ? bias[o] : 0.f;
#pragma unroll
                for (int ni = 0; ni < 4; ni++) {
                    int t = t0 + tsub + ni * 16 + lr;
                    size_t oidx = ((size_t)b * CQ + o) * TT + t;
                    float v = acc[mi][ni][reg] + bv;
                    if (EPI == 2) {
                        outf[oidx] = v + query[oidx] * qsc[b * CQ + o] + qsh[b * CQ + o];
                    } else {
                        outb[oidx] = f2bf(v);
                    }
                }
            }
    }
}

// ---- flash attention v4: LDS-staged K/V tiles, 8 waves, 1 block/CU ----
__global__ __launch_bounds__(512, 2) void flash_kernel(
        const u16* __restrict__ qqT, const u16* __restrict__ kkT,
        const u16* __restrict__ vv, const float* __restrict__ WM,
        u16* __restrict__ aT) {
    int b = blockIdx.y;
    int T0 = blockIdx.x * 64;
    int wid = threadIdx.x >> 6, lane = threadIdx.x & 63;
    int lr = lane & 15, lg = lane >> 4;
    int tb = wid >> 1, sb = wid & 1;

    __shared__ u16 K_lds[64][512];   // [s][c], chunk-swizzled by (s&7)
    __shared__ u16 V_lds[512][64];   // [c][s], chunk-swizzled by (c&7)
    __shared__ u16 p_lds[64][64];    // [t][s], chunk-swizzled by (t&7)
    __shared__ float ex_max[64][2];
    __shared__ float ex_sum[64][2];

    bf16x8 qf[16];
    {
        const u16* qrow = qqT + ((size_t)b * TT + T0 + 16 * tb + lr) * CQ + lg * 8;
#pragma unroll
        for (int kc = 0; kc < 16; kc++) qf[kc] = *(const bf16x8*)(qrow + kc * 32);
    }
    f32x4 acc[16];
#pragma unroll
    for (int i = 0; i < 16; i++) acc[i] = f32x4{0.f, 0.f, 0.f, 0.f};
    float m[4], l[4];
#pragma unroll
    for (int r = 0; r < 4; r++) { m[r] = -1e30f; l[r] = 0.f; }

    const float* wmrow = WM + ((size_t)b * TT + T0 + 16 * tb + 4 * lg) * TT + 32 * sb + lr;
    const char* kbase = (const char*)(kkT + ((size_t)b * TT) * CQ);
    int myt = 16 * tb + 4 * lg;

    for (int s0 = 0; s0 < TT; s0 += 64) {
        __syncthreads();  // bar1
#pragma unroll
        for (int i = 0; i < 8; i++) {
            int s = wid * 8 + i;
            gload_lds16(kbase + ((size_t)(s0 + s)) * 1024 + ((lane ^ (s & 7)) << 4),
                        &K_lds[s][0]);
        }
#pragma unroll
        for (int g2 = 0; g2 < 8; g2++) {
            int c0 = (wid * 8 + g2) * 8;
            int c = c0 + (lane >> 3);
            gload_lds16((const char*)(vv + ((size_t)b * CQ + c) * TT + s0) +
                            ((((lane & 7) ^ (c & 7))) << 4),
                        &V_lds[c0][0]);
        }
        float wmv[2][4];
#pragma unroll
        for (int fs = 0; fs < 2; fs++)
#pragma unroll
            for (int reg = 0; reg < 4; reg++)
                wmv[fs][reg] = wmrow[(size_t)reg * TT + s0 + fs * 16];
        __syncthreads();  // bar2

        f32x4 sacc[2];
        sacc[0] = f32x4{0.f, 0.f, 0.f, 0.f};
        sacc[1] = f32x4{0.f, 0.f, 0.f, 0.f};
#pragma unroll
        for (int kc = 0; kc < 16; kc++) {
#pragma unroll
            for (int fs = 0; fs < 2; fs++) {
                const char* kp = (const char*)&K_lds[32 * sb + fs * 16 + lr][0];
                bf16x8 kfr = *(const bf16x8*)(kp + ((((kc << 2) | lg) ^ (lr & 7)) << 4));
                sacc[fs] = __builtin_amdgcn_mfma_f32_16x16x32_bf16(qf[kc], kfr, sacc[fs], 0, 0, 0);
            }
        }
        float lgt[2][4], pmax[4];
#pragma unroll
        for (int r = 0; r < 4; r++) pmax[r] = -3e38f;
#pragma unroll
        for (int fs = 0; fs < 2; fs++)
#pragma unroll
            for (int reg = 0; reg < 4; reg++) {
                float v = sacc[fs][reg] * wmv[fs][reg];
                lgt[fs][reg] = v;
                pmax[reg] = fmaxf(pmax[reg], v);
            }
#pragma unroll
        for (int d = 1; d < 16; d <<= 1)
#pragma unroll
            for (int reg = 0; reg < 4; reg++)
                pmax[reg] = fmaxf(pmax[reg], __shfl_xor(pmax[reg], d, 64));
        if (lr == 0) {
#pragma unroll
            for (int reg = 0; reg < 4; reg++) ex_max[myt + reg][sb] = pmax[reg];
        }
        __syncthreads();  // bar3
        float fac[4], rsum[4];
#pragma unroll
        for (int reg = 0; reg < 4; reg++) {
            int t = myt + reg;
            float mn = fmaxf(m[reg], fmaxf(ex_max[t][0], ex_max[t][1]));
            fac[reg] = __expf(m[reg] - mn);
            m[reg] = mn;
            rsum[reg] = 0.f;
        }
#pragma unroll
        for (int fs = 0; fs < 2; fs++)
#pragma unroll
            for (int reg = 0; reg < 4; reg++) {
                float p = __expf(lgt[fs][reg] - m[reg]);
                rsum[reg] += p;
                int t = myt + reg;
                int s = 32 * sb + fs * 16 + lr;
                *(u16*)((char*)p_lds + t * 128 + ((((s >> 3) ^ (t & 7))) << 4) + ((s & 7) << 1)) = f2bf(p);
            }
#pragma unroll
        for (int d = 1; d < 16; d <<= 1)
#pragma unroll
            for (int reg = 0; reg < 4; reg++)
                rsum[reg] += __shfl_xor(rsum[reg], d, 64);
        if (lr == 0) {
#pragma unroll
            for (int reg = 0; reg < 4; reg++) ex_sum[myt + reg][sb] = rsum[reg];
        }
        __syncthreads();  // bar4
#pragma unroll
        for (int reg = 0; reg < 4; reg++) {
            int t = myt + reg;
            l[reg] = l[reg] * fac[reg] + ex_sum[t][0] + ex_sum[t][1];
        }
#pragma unroll
        for (int nt = 0; nt < 16; nt++)
#pragma unroll
            for (int reg = 0; reg < 4; reg++) acc[nt][reg] *= fac[reg];
#pragma unroll
        for (int ks = 0; ks < 2; ks++) {
            int prow = 16 * tb + lr;
            bf16x8 pa = *(const bf16x8*)((const char*)p_lds + prow * 128 +
                                         ((((ks << 2) | lg) ^ (lr & 7)) << 4));
#pragma unroll
            for (int nt = 0; nt < 16; nt++) {
                int vr = 256 * sb + nt * 16 + lr;
                bf16x8 vf = *(const bf16x8*)((const char*)&V_lds[vr][0] +
                                             ((((ks << 2) | lg) ^ (lr & 7)) << 4));
                acc[nt] = __builtin_amdgcn_mfma_f32_16x16x32_bf16(pa, vf, acc[nt], 0, 0, 0);
            }
        }
    }
    float inv[4];
#pragma unroll
    for (int reg = 0; reg < 4; reg++) inv[reg] = 1.f / l[reg];
#pragma unroll
    for (int nt = 0; nt < 16; nt++)
#pragma unroll
        for (int reg = 0; reg < 4; reg++) {
            int t = T0 + myt + reg;
            int c = 256 * sb + nt * 16 + lr;
            aT[((size_t)b * TT + t) * CQ + c] = f2bf(acc[nt][reg] * inv[reg]);
        }
}

extern "C" void kernel_launch(void* const* d_in, const int* in_sizes, int n_in,
                              void* d_out, int out_size, void* d_ws, size_t ws_size,
                              hipStream_t stream) {
    const float* key_feat = (const float*)d_in[0];
    const float* query    = (const float*)d_in[1];
    const float* WM       = (const float*)d_in[2];
    const float* kpw      = (const float*)d_in[3];
    const float* norm_w   = (const float*)d_in[4];
    const float* norm_b   = (const float*)d_in[5];
    const float* qkv_w    = (const float*)d_in[6];
    const float* qkv_b    = (const float*)d_in[7];
    const float* proj_w   = (const float*)d_in[8];
    const float* proj_b   = (const float*)d_in[9];
    float* out = (float*)d_out;
    char* ws = (char*)d_ws;

    u16* kdsT = (u16*)(ws);                 // [0, 8.4M)   dead after kraw gemm
    u16* kraw = (u16*)(ws + 8388608);       // [8.4, 25.2M) dead after affine#2
    u16* qnT  = (u16*)(ws + 25165824);      // dead after qkv gemms
    u16* knT  = (u16*)(ws + 41943040);      // dead after qkv gemms
    u16* qqT  = (u16*)(ws + 58720256);
    u16* kkT  = (u16*)(ws + 75497472);
    u16* vvp  = (u16*)(ws + 92274688);
    u16* aT   = (u16*)(ws);                 // [0, 16.8M) over kdsT+kraw head (dead by flash)
    u16* wqkv = (u16*)(ws + 16777216);      // [16.78, 19.92M) over kraw tail, written after affine#2
    u16* wproj= (u16*)(ws + 19922944);      // [19.92, 20.45M)
    float* qsc = (float*)(ws + 109051904);
    float* qsh = qsc + NB * CQ;
    float* ksc = qsh + NB * CQ;
    float* ksh = ksc + NB * CQ;
    u16* wkp  = (u16*)(ws + 109084672);     // 256KB (proven region)

    // 0. convert key_proj_w to bf16
    wconv_kernel<<<64, 256, 0, stream>>>(kpw, wkp, 512 * 256, 0);
    // 1. pool + transpose
    pool_tr_kernel<<<dim3(64, NB), 256, 0, stream>>>(key_feat, kdsT);
    // 2. k_raw = key_proj_w @ kds   (staged GEMM)
    gemm_st_kernel<0, 0, 0><<<dim3(4, 32, NB), 256, 0, stream>>>(
        wkp, kdsT, nullptr, CK, nullptr, kraw, nullptr, nullptr, nullptr, nullptr, nullptr);
    // 3. group-norm stats
    gn_stats_kernel<0><<<dim3(32, NB), 256, 0, stream>>>(query, norm_w, norm_b, qsc, qsh);
    gn_stats_kernel<1><<<dim3(32, NB), 256, 0, stream>>>(kraw, norm_w, norm_b, ksc, ksh);
    // 4. normalized, transposed activations
    affine_tr_kernel<0><<<dim3(64, 8, NB), 256, 0, stream>>>(query, qsc, qsh, qnT);
    affine_tr_kernel<1><<<dim3(64, 8, NB), 256, 0, stream>>>(kraw, ksc, ksh, knT);
    // 4b. convert qkv_w (q/k rows pre-scaled) + proj_w to bf16 (kraw now dead)
    wconv_kernel<<<768, 256, 0, stream>>>(qkv_w, wqkv, 1536 * 1024, 1024 * 1024);
    wconv_kernel<<<128, 256, 0, stream>>>(proj_w, wproj, 512 * 512, 0);
    // 5. qkv projection: qq/kk swapped+transposed store, vv natural
    gemm_st_kernel<1, 1, 1><<<dim3(8, 32, NB), 256, 0, stream>>>(
        wqkv, qnT, knT, 1024, qkv_b, qqT, kkT, nullptr, nullptr, nullptr, nullptr);
    gemm_st_kernel<1, 1, 0><<<dim3(4, 32, NB), 256, 0, stream>>>(
        wqkv + (size_t)1024 * 1024, qnT, knT, 1024, qkv_b + 1024, vvp, nullptr, nullptr,
        nullptr, nullptr, nullptr);
    // 6. flash attention (LDS-staged, 1 block/CU)
    flash_kernel<<<dim3(64, NB), 512, 0, stream>>>(qqT, kkT, vvp, WM, aT);
    // 7. out = GN(query) + proj_w @ a + proj_b
    gemm_st_kernel<2, 0, 0><<<dim3(4, 32, NB), 256, 0, stream>>>(
        wproj, aT, nullptr, CQ, proj_b, nullptr, nullptr, out, query, qsc, qsh);
}